// Round 2
// baseline (1100.538 us; speedup 1.0000x reference)
//
#include <hip/hip_runtime.h>
#include <math.h>

// ---------------------------------------------------------------------------
// TypeGraphModel: conv encoder + transformer + heads. All fp32.
// Sizes: N=1024, D=1024, CC=64, TP=16, EMB=128, NH=4, HD=32, L=2, FF=2048
// ---------------------------------------------------------------------------

__device__ __forceinline__ float gelu_f(float v) {
  return 0.5f * v * (1.f + erff(v * 0.70710678118654752440f));
}

// ---------------- fused conv1+bn+gelu -> conv2+bn+gelu+pool -----------------
// Grid: 4096 blocks = 1024 sensors x 4 quarters of 256 positions.
__global__ __launch_bounds__(256) void encoder_kernel(
    const float* __restrict__ x,
    const float* __restrict__ w1, const float* __restrict__ b1,
    const float* __restrict__ g1, const float* __restrict__ be1,
    const float* __restrict__ m1, const float* __restrict__ v1,
    const float* __restrict__ w2, const float* __restrict__ b2,
    const float* __restrict__ g2, const float* __restrict__ be2,
    const float* __restrict__ m2, const float* __restrict__ v2,
    float* __restrict__ pooled)
{
  const int blk = blockIdx.x;
  const int n = blk >> 2, qq = blk & 3;
  const int P0 = qq * 256;
  const int tid = threadIdx.x;

  __shared__ float xs[272];          // x[P0-5 .. P0+262], zero padded
  __shared__ float h1s[32][260];     // h1 positions P0-2 .. P0+257
  __shared__ float s1[32], t1[32], s2s[64], t2s[64];

  if (tid < 32) {
    float s = g1[tid] * rsqrtf(v1[tid] + 1e-5f);
    s1[tid] = s; t1[tid] = (b1[tid] - m1[tid]) * s + be1[tid];
  } else if (tid < 96) {
    int c = tid - 32;
    float s = g2[c] * rsqrtf(v2[c] + 1e-5f);
    s2s[c] = s; t2s[c] = (b2[c] - m2[c]) * s + be2[c];
  }
  for (int j = tid; j < 268; j += 256) {
    int gp = P0 - 5 + j;
    xs[j] = (gp >= 0 && gp < 1024) ? x[n * 1024 + gp] : 0.f;
  }
  __syncthreads();

  // conv1 (1->32ch, k=7, pad3) + bn1 + gelu into LDS
  for (int c = 0; c < 32; c++) {
    float wk[7];
#pragma unroll
    for (int k = 0; k < 7; k++) wk[k] = w1[c * 7 + k];
    const float sc = s1[c], sh = t1[c];
    for (int p = tid; p < 260; p += 256) {
      int pos = P0 - 2 + p;
      float acc = 0.f;
#pragma unroll
      for (int k = 0; k < 7; k++) acc += wk[k] * xs[p + k];
      float hv = gelu_f(acc * sc + sh);
      h1s[c][p] = (pos >= 0 && pos < 1024) ? hv : 0.f;  // conv2 zero-pad
    }
  }
  __syncthreads();

  // conv2 (32->64ch, k=5, pad2) + bn2 + gelu + mean-pool(64)
  const int o = tid >> 2, qd = tid & 3;
  const float sc2 = s2s[o], sh2 = t2s[o];
  float seg[4] = {0.f, 0.f, 0.f, 0.f};
#pragma unroll
  for (int s8 = 0; s8 < 8; s8++) {
    const int ch = s8 * 4 + qd;
    const int pl0 = ch * 8;
    float acc[8] = {0.f,0.f,0.f,0.f,0.f,0.f,0.f,0.f};
    for (int i = 0; i < 32; i++) {
      const float* hp = &h1s[i][pl0];
      float4 a = *(const float4*)(hp);
      float4 bq = *(const float4*)(hp + 4);
      float4 cq = *(const float4*)(hp + 8);
      float hv[12] = {a.x,a.y,a.z,a.w, bq.x,bq.y,bq.z,bq.w, cq.x,cq.y,cq.z,cq.w};
      const float* wp = w2 + (o * 32 + i) * 5;
      float wv0 = wp[0], wv1 = wp[1], wv2 = wp[2], wv3 = wp[3], wv4 = wp[4];
#pragma unroll
      for (int pp = 0; pp < 8; pp++) {
        float s = wv0 * hv[pp] + wv1 * hv[pp + 1];
        s += wv2 * hv[pp + 2];
        s += wv3 * hv[pp + 3];
        s += wv4 * hv[pp + 4];
        acc[pp] += s;
      }
    }
    float part = 0.f;
#pragma unroll
    for (int pp = 0; pp < 8; pp++) part += gelu_f(acc[pp] * sc2 + sh2);
    seg[s8 >> 1] += part;   // ch>>3 == (s8*4+qd)>>3 == s8>>1
  }
#pragma unroll
  for (int s = 0; s < 4; s++) {
    seg[s] += __shfl_xor(seg[s], 1);
    seg[s] += __shfl_xor(seg[s], 2);
  }
  if (qd == 0) {
#pragma unroll
    for (int s = 0; s < 4; s++)
      pooled[(n * 64 + o) * 16 + qq * 4 + s] = seg[s] * (1.f / 64.f);
  }
}

// ---------------- generic fp32 GEMM-NT: C = act(scale*A@W^T + bias + R) -----
template<int BN, int TN, bool RELU>
__global__ __launch_bounds__(256) void gemm_nt(
    const float* __restrict__ A, int lda, int strideA,
    const float* __restrict__ W, int ldw, int strideW,
    const float* __restrict__ bias,
    const float* __restrict__ R,
    float* __restrict__ C, int ldc, long long strideC,
    int K, float scale)
{
  const int m0 = blockIdx.x * 32;
  const int n0 = blockIdx.y * BN;
  A += (size_t)blockIdx.z * strideA;
  W += (size_t)blockIdx.z * strideW;
  C += (size_t)blockIdx.z * strideC;

  __shared__ float As[32][33];
  __shared__ float Ws[32][BN + 1];
  const int tid = threadIdx.x;
  const int tm = (tid & 15) * 2;
  const int tn = (tid >> 4) * TN;
  float acc[2][TN];
#pragma unroll
  for (int i = 0; i < 2; i++)
#pragma unroll
    for (int j = 0; j < TN; j++) acc[i][j] = 0.f;

  const int ar = tid >> 3, kq = (tid & 7) * 4;
  for (int k0 = 0; k0 < K; k0 += 32) {
    float4 av = *(const float4*)(A + (size_t)(m0 + ar) * lda + k0 + kq);
    As[kq][ar] = av.x; As[kq + 1][ar] = av.y;
    As[kq + 2][ar] = av.z; As[kq + 3][ar] = av.w;
#pragma unroll
    for (int rr = 0; rr < BN / 32; rr++) {
      int r = ar + rr * 32;
      float4 wv = *(const float4*)(W + (size_t)(n0 + r) * ldw + k0 + kq);
      Ws[kq][r] = wv.x; Ws[kq + 1][r] = wv.y;
      Ws[kq + 2][r] = wv.z; Ws[kq + 3][r] = wv.w;
    }
    __syncthreads();
#pragma unroll
    for (int k = 0; k < 32; k++) {
      float a0 = As[k][tm], a1 = As[k][tm + 1];
#pragma unroll
      for (int j = 0; j < TN; j++) {
        float bv = Ws[k][tn + j];
        acc[0][j] += a0 * bv;
        acc[1][j] += a1 * bv;
      }
    }
    __syncthreads();
  }
#pragma unroll
  for (int ii = 0; ii < 2; ii++) {
    int m = m0 + tm + ii;
#pragma unroll
    for (int j = 0; j < TN; j++) {
      int nn = n0 + tn + j;
      float v = acc[ii][j] * scale;
      if (bias) v += bias[nn];
      if (R) v += R[(size_t)m * ldc + nn];
      if (RELU) v = fmaxf(v, 0.f);
      C[(size_t)m * ldc + nn] = v;
    }
  }
}

// ---------------- PV: O[i, h*32+d] = sum_j P[z,i,j] * V[j, h*32+d] ----------
// h = h0 + blockIdx.z ; S holds blockIdx.z-indexed heads.
__global__ __launch_bounds__(256) void pv_kernel(
    const float* __restrict__ S, const float* __restrict__ qkv,
    float* __restrict__ O, int h0)
{
  const int m0 = blockIdx.x * 32;
  const int h = h0 + blockIdx.z;
  const float* A = S + (size_t)blockIdx.z * 1024 * 1024;  // lda 1024
  const float* B = qkv + 256 + h * 32;                    // ldb 384, 32 cols
  __shared__ float As[32][33];
  __shared__ float Bs[32][33];
  const int tid = threadIdx.x;
  const int tm = (tid & 15) * 2, tn = (tid >> 4) * 2;
  float acc[2][2] = {{0.f,0.f},{0.f,0.f}};
  const int r = tid >> 3, q4 = (tid & 7) * 4;
  for (int k0 = 0; k0 < 1024; k0 += 32) {
    float4 av = *(const float4*)(A + (size_t)(m0 + r) * 1024 + k0 + q4);
    As[q4][r] = av.x; As[q4 + 1][r] = av.y; As[q4 + 2][r] = av.z; As[q4 + 3][r] = av.w;
    float4 bv = *(const float4*)(B + (size_t)(k0 + r) * 384 + q4);
    Bs[r][q4] = bv.x; Bs[r][q4 + 1] = bv.y; Bs[r][q4 + 2] = bv.z; Bs[r][q4 + 3] = bv.w;
    __syncthreads();
#pragma unroll
    for (int k = 0; k < 32; k++) {
      float a0 = As[k][tm], a1 = As[k][tm + 1];
      float b0 = Bs[k][tn], b1 = Bs[k][tn + 1];
      acc[0][0] += a0 * b0; acc[0][1] += a0 * b1;
      acc[1][0] += a1 * b0; acc[1][1] += a1 * b1;
    }
    __syncthreads();
  }
#pragma unroll
  for (int ii = 0; ii < 2; ii++)
#pragma unroll
    for (int jj = 0; jj < 2; jj++)
      O[(size_t)(m0 + tm + ii) * 128 + h * 32 + tn + jj] = acc[ii][jj];
}

// ---------------- row softmax over 1024, 4 rows per block (1 wave each) ----
__global__ __launch_bounds__(256) void softmax_kernel(float* __restrict__ S)
{
  int row = blockIdx.x * 4 + (threadIdx.x >> 6);
  int lane = threadIdx.x & 63;
  float* p = S + (size_t)row * 1024 + lane * 4;
  float4 v[4];
  float mx = -3.4e38f;
#pragma unroll
  for (int j = 0; j < 4; j++) {
    v[j] = *(float4*)(p + j * 256);
    mx = fmaxf(mx, fmaxf(fmaxf(v[j].x, v[j].y), fmaxf(v[j].z, v[j].w)));
  }
#pragma unroll
  for (int off = 32; off >= 1; off >>= 1) mx = fmaxf(mx, __shfl_xor(mx, off));
  float sum = 0.f;
#pragma unroll
  for (int j = 0; j < 4; j++) {
    v[j].x = __expf(v[j].x - mx); v[j].y = __expf(v[j].y - mx);
    v[j].z = __expf(v[j].z - mx); v[j].w = __expf(v[j].w - mx);
    sum += v[j].x + v[j].y + v[j].z + v[j].w;
  }
#pragma unroll
  for (int off = 32; off >= 1; off >>= 1) sum += __shfl_xor(sum, off);
  float inv = 1.f / sum;
#pragma unroll
  for (int j = 0; j < 4; j++) {
    v[j].x *= inv; v[j].y *= inv; v[j].z *= inv; v[j].w *= inv;
    *(float4*)(p + j * 256) = v[j];
  }
}

// ---------------- LayerNorm(128) in place, 4 rows/block -------------------
__global__ __launch_bounds__(256) void ln_kernel(
    float* __restrict__ t, const float* __restrict__ g, const float* __restrict__ b)
{
  int row = blockIdx.x * 4 + (threadIdx.x >> 6);
  int lane = threadIdx.x & 63;
  float* p = t + (size_t)row * 128 + lane * 2;
  float2 v = *(float2*)p;
  float s = v.x + v.y;
#pragma unroll
  for (int off = 32; off >= 1; off >>= 1) s += __shfl_xor(s, off);
  float mu = s * (1.f / 128.f);
  float dx = v.x - mu, dy = v.y - mu;
  float q = dx * dx + dy * dy;
#pragma unroll
  for (int off = 32; off >= 1; off >>= 1) q += __shfl_xor(q, off);
  float inv = rsqrtf(q * (1.f / 128.f) + 1e-5f);
  float2 gv = *(const float2*)(g + lane * 2);
  float2 bv = *(const float2*)(b + lane * 2);
  float2 o = make_float2(dx * inv * gv.x + bv.x, dy * inv * gv.y + bv.y);
  *(float2*)p = o;
}

// ---------------- node head second layer (N=3) -----------------------------
__global__ __launch_bounds__(256) void nh2_kernel(
    const float* __restrict__ mid, const float* __restrict__ w,
    const float* __restrict__ b, float* __restrict__ out)
{
  int m = blockIdx.x * 256 + threadIdx.x;   // 1024 rows
  const float* row = mid + (size_t)m * 128;
  float a0 = 0.f, a1 = 0.f, a2 = 0.f;
#pragma unroll 4
  for (int k = 0; k < 128; k++) {
    float xv = row[k];
    a0 += xv * w[k]; a1 += xv * w[128 + k]; a2 += xv * w[256 + k];
  }
  out[m * 3 + 0] = a0 + b[0];
  out[m * 3 + 1] = a1 + b[1];
  out[m * 3 + 2] = a2 + b[2];
}

// ---------------- all-pairs edge: out[i,j] = relu(hi[i]+hjb[j]).w + e2b ----
__global__ __launch_bounds__(256) void edge_kernel(
    const float* __restrict__ hi, const float* __restrict__ hjb,
    const float* __restrict__ w, const float* __restrict__ e2b,
    float* __restrict__ out)
{
  const int i0 = blockIdx.x * 64;
  const int j0 = blockIdx.y * 32;
  __shared__ float his[128][64];
  __shared__ float hjs[128][32];
  const int tid = threadIdx.x;
  {
    int r = tid >> 2, c0 = (tid & 3) * 32;
#pragma unroll
    for (int u = 0; u < 8; u++) {
      float4 v = *(const float4*)(hi + (size_t)(i0 + r) * 128 + c0 + u * 4);
      his[c0 + u * 4 + 0][r] = v.x; his[c0 + u * 4 + 1][r] = v.y;
      his[c0 + u * 4 + 2][r] = v.z; his[c0 + u * 4 + 3][r] = v.w;
    }
  }
  {
    int r = tid >> 3, c0 = (tid & 7) * 16;
#pragma unroll
    for (int u = 0; u < 4; u++) {
      float4 v = *(const float4*)(hjb + (size_t)(j0 + r) * 128 + c0 + u * 4);
      hjs[c0 + u * 4 + 0][r] = v.x; hjs[c0 + u * 4 + 1][r] = v.y;
      hjs[c0 + u * 4 + 2][r] = v.z; hjs[c0 + u * 4 + 3][r] = v.w;
    }
  }
  __syncthreads();
  const int il = (tid & 15) * 4, jl = (tid >> 4) * 2;
  float acc[4][2] = {{0.f,0.f},{0.f,0.f},{0.f,0.f},{0.f,0.f}};
  for (int e = 0; e < 128; e++) {
    float4 a = *(const float4*)&his[e][il];
    float2 bv = *(const float2*)&hjs[e][jl];
    float we = w[e];
    float av[4] = {a.x, a.y, a.z, a.w};
    float bb[2] = {bv.x, bv.y};
#pragma unroll
    for (int ii = 0; ii < 4; ii++)
#pragma unroll
      for (int jj = 0; jj < 2; jj++)
        acc[ii][jj] += fmaxf(av[ii] + bb[jj], 0.f) * we;
  }
  float eb = e2b[0];
#pragma unroll
  for (int ii = 0; ii < 4; ii++) {
    float2 vv = make_float2(acc[ii][0] + eb, acc[ii][1] + eb);
    *(float2*)(out + (size_t)(i0 + il + ii) * 1024 + j0 + jl) = vv;
  }
}

// ---------------------------------------------------------------------------
extern "C" void kernel_launch(void* const* d_in, const int* in_sizes, int n_in,
                              void* d_out, int out_size, void* d_ws, size_t ws_size,
                              hipStream_t stream)
{
  const float* x        = (const float*)d_in[0];
  const float* conv1_w  = (const float*)d_in[1];
  const float* conv1_b  = (const float*)d_in[2];
  const float* bn1_g    = (const float*)d_in[3];
  const float* bn1_b    = (const float*)d_in[4];
  const float* bn1_m    = (const float*)d_in[5];
  const float* bn1_v    = (const float*)d_in[6];
  const float* conv2_w  = (const float*)d_in[7];
  const float* conv2_b  = (const float*)d_in[8];
  const float* bn2_g    = (const float*)d_in[9];
  const float* bn2_b    = (const float*)d_in[10];
  const float* bn2_m    = (const float*)d_in[11];
  const float* bn2_v    = (const float*)d_in[12];
  const float* proj_w   = (const float*)d_in[13];
  const float* proj_b   = (const float*)d_in[14];
  const float* attn_in_w  = (const float*)d_in[15];
  const float* attn_in_b  = (const float*)d_in[16];
  const float* attn_out_w = (const float*)d_in[17];
  const float* attn_out_b = (const float*)d_in[18];
  const float* ln1_g    = (const float*)d_in[19];
  const float* ln1_b    = (const float*)d_in[20];
  const float* ff1_w    = (const float*)d_in[21];
  const float* ff1_b    = (const float*)d_in[22];
  const float* ff2_w    = (const float*)d_in[23];
  const float* ff2_b    = (const float*)d_in[24];
  const float* ln2_g    = (const float*)d_in[25];
  const float* ln2_b    = (const float*)d_in[26];
  const float* nh1_w    = (const float*)d_in[27];
  const float* nh1_b    = (const float*)d_in[28];
  const float* nh2_w    = (const float*)d_in[29];
  const float* nh2_b    = (const float*)d_in[30];
  const float* e1_w     = (const float*)d_in[31];
  const float* e1_b     = (const float*)d_in[32];
  const float* e2_w     = (const float*)d_in[33];
  const float* e2_b     = (const float*)d_in[34];
  const float* p1_w     = (const float*)d_in[35];
  const float* p1_b     = (const float*)d_in[36];
  const float* p2_w     = (const float*)d_in[37];
  const float* p2_b     = (const float*)d_in[38];

  float* ws = (float*)d_ws;

  // Two arena layouts, chosen by actual ws_size (host-side, deterministic).
  // FULL:    R = 16MiB shared region (pooled | Sbuf x4 heads | fbuf full)
  //          total 5,636,096 floats = 21.5 MiB
  // COMPACT: R =  4MiB shared region (pooled | S 1 head | fbuf half)
  //          total 2,490,368 floats = 9.5 MiB
  const bool full = (ws_size >= (size_t)5636096 * 4);
  const size_t RN = full ? 4194304 : 1048576;
  float* R      = ws;                  // pooled / Sbuf / fbuf share this
  float* z      = ws + RN;
  float* tA     = z + 131072;
  float* tB     = tA + 131072;
  float* qkvb   = tB + 131072;         // 1024*384
  float* attnO  = qkvb + 393216;
  float* hib    = attnO + 131072;
  float* hjbb   = hib + 131072;
  float* nhmid  = hjbb + 131072;
  float* pmid   = nhmid + 131072;

  float* pooled = R;                   // 1024*1024 (both layouts)
  float* Sbuf   = R;                   // full: 4 heads; compact: 1 head
  float* fbuf   = R;                   // full: 1024*2048; compact: 1024*1024

  float* out_node = (float*)d_out;
  float* out_edge = out_node + 3072;
  float* out_proj = out_edge + 1048576;

  const float iso = 0.17677669529663689f;  // 1/sqrt(32)

  // ---- sensor temporal encoder (fused) ----
  encoder_kernel<<<4096, 256, 0, stream>>>(
      x, conv1_w, conv1_b, bn1_g, bn1_b, bn1_m, bn1_v,
      conv2_w, conv2_b, bn2_g, bn2_b, bn2_m, bn2_v, pooled);

  // z = pooled @ proj_w^T + proj_b   (reads R, writes z; R free afterwards)
  gemm_nt<32, 2, false><<<dim3(32, 4, 1), 256, 0, stream>>>(
      pooled, 1024, 0, proj_w, 1024, 0, proj_b, nullptr, z, 128, 0, 1024, 1.f);

  // ---- transformer layers ----
  for (int l = 0; l < 2; l++) {
    const float* tIn = l ? tA : z;
    gemm_nt<32, 2, false><<<dim3(32, 12, 1), 256, 0, stream>>>(
        tIn, 128, 0, attn_in_w + l * 384 * 128, 128, 0,
        attn_in_b + l * 384, nullptr, qkvb, 384, 0, 128, 1.f);

    if (full) {
      gemm_nt<32, 2, false><<<dim3(32, 32, 4), 256, 0, stream>>>(
          qkvb, 384, 32, qkvb + 128, 384, 32, nullptr, nullptr,
          Sbuf, 1024, 1048576LL, 32, iso);
      softmax_kernel<<<1024, 256, 0, stream>>>(Sbuf);
      pv_kernel<<<dim3(32, 1, 4), 256, 0, stream>>>(Sbuf, qkvb, attnO, 0);
    } else {
      for (int h = 0; h < 4; h++) {
        gemm_nt<32, 2, false><<<dim3(32, 32, 1), 256, 0, stream>>>(
            qkvb + h * 32, 384, 0, qkvb + 128 + h * 32, 384, 0,
            nullptr, nullptr, Sbuf, 1024, 0, 32, iso);
        softmax_kernel<<<256, 256, 0, stream>>>(Sbuf);
        pv_kernel<<<dim3(32, 1, 1), 256, 0, stream>>>(Sbuf, qkvb, attnO, h);
      }
    }

    // pre1 = tIn + attnO @ Wo^T + bo
    gemm_nt<32, 2, false><<<dim3(32, 4, 1), 256, 0, stream>>>(
        attnO, 128, 0, attn_out_w + l * 128 * 128, 128, 0,
        attn_out_b + l * 128, tIn, tB, 128, 0, 128, 1.f);
    ln_kernel<<<256, 256, 0, stream>>>(tB, ln1_g + l * 128, ln1_b + l * 128);

    if (full) {
      gemm_nt<64, 4, true><<<dim3(32, 32, 1), 256, 0, stream>>>(
          tB, 128, 0, ff1_w + l * 2048 * 128, 128, 0,
          ff1_b + l * 2048, nullptr, fbuf, 2048, 0, 128, 1.f);
      gemm_nt<32, 2, false><<<dim3(32, 4, 1), 256, 0, stream>>>(
          fbuf, 2048, 0, ff2_w + l * 128 * 2048, 2048, 0,
          ff2_b + l * 128, tB, tA, 128, 0, 2048, 1.f);
    } else {
      // split-K FFN: two halves of FF, fbuf holds 1024 cols at a time
      gemm_nt<64, 4, true><<<dim3(32, 16, 1), 256, 0, stream>>>(
          tB, 128, 0, ff1_w + l * 2048 * 128, 128, 0,
          ff1_b + l * 2048, nullptr, fbuf, 1024, 0, 128, 1.f);
      gemm_nt<32, 2, false><<<dim3(32, 4, 1), 256, 0, stream>>>(
          fbuf, 1024, 0, ff2_w + l * 128 * 2048, 2048, 0,
          ff2_b + l * 128, tB, tA, 128, 0, 1024, 1.f);
      gemm_nt<64, 4, true><<<dim3(32, 16, 1), 256, 0, stream>>>(
          tB, 128, 0, ff1_w + l * 2048 * 128 + 1024 * 128, 128, 0,
          ff1_b + l * 2048 + 1024, nullptr, fbuf, 1024, 0, 128, 1.f);
      gemm_nt<32, 2, false><<<dim3(32, 4, 1), 256, 0, stream>>>(
          fbuf, 1024, 0, ff2_w + l * 128 * 2048 + 1024, 2048, 0,
          nullptr, tA, tA, 128, 0, 1024, 1.f);
    }
    ln_kernel<<<256, 256, 0, stream>>>(tA, ln2_g + l * 128, ln2_b + l * 128);
  }

  // ---- node head ----
  gemm_nt<32, 2, true><<<dim3(32, 4, 1), 256, 0, stream>>>(
      tA, 128, 0, nh1_w, 128, 0, nh1_b, nullptr, nhmid, 128, 0, 128, 1.f);
  nh2_kernel<<<4, 256, 0, stream>>>(nhmid, nh2_w, nh2_b, out_node);

  // ---- edge MLP ----
  gemm_nt<32, 2, false><<<dim3(32, 4, 1), 256, 0, stream>>>(
      tA, 128, 0, e1_w, 256, 0, nullptr, nullptr, hib, 128, 0, 128, 1.f);
  gemm_nt<32, 2, false><<<dim3(32, 4, 1), 256, 0, stream>>>(
      tA, 128, 0, e1_w + 128, 256, 0, e1_b, nullptr, hjbb, 128, 0, 128, 1.f);
  edge_kernel<<<dim3(16, 32), 256, 0, stream>>>(hib, hjbb, e2_w, e2_b, out_edge);

  // ---- projector (on z) ----
  gemm_nt<32, 2, true><<<dim3(32, 4, 1), 256, 0, stream>>>(
      z, 128, 0, p1_w, 128, 0, p1_b, nullptr, pmid, 128, 0, 128, 1.f);
  gemm_nt<32, 2, false><<<dim3(32, 4, 1), 256, 0, stream>>>(
      pmid, 128, 0, p2_w, 128, 0, p2_b, nullptr, out_proj, 128, 0, 128, 1.f);
}

// Round 3
// 609.266 us; speedup vs baseline: 1.8063x; 1.8063x over previous
//
#include <hip/hip_runtime.h>
#include <math.h>

// ---------------------------------------------------------------------------
// TypeGraphModel: conv encoder (bf16 MFMA) + transformer + heads.
// Sizes: N=1024, D=1024, CC=64, TP=16, EMB=128, NH=4, HD=32, L=2, FF=2048
// ---------------------------------------------------------------------------

typedef float f32x4 __attribute__((ext_vector_type(4)));
typedef short bf16x8 __attribute__((ext_vector_type(8)));

// Abramowitz-Stegun 7.1.26 erf (max abs err 1.5e-7) -> exact-GELU
__device__ __forceinline__ float gelu_fast(float v) {
  float ax = fabsf(v) * 0.70710678118654752440f;
  float t = __builtin_amdgcn_rcpf(fmaf(0.3275911f, ax, 1.f));
  float p = fmaf(1.061405429f, t, -1.453152027f);
  p = fmaf(p, t, 1.421413741f);
  p = fmaf(p, t, -0.284496736f);
  p = fmaf(p, t, 0.254829592f);
  p = p * t;
  float e = __expf(-ax * ax);
  float erfa = fmaf(-p, e, 1.f);
  float erfv = copysignf(erfa, v);
  return 0.5f * v * (1.f + erfv);
}

__device__ __forceinline__ unsigned short to_bf16(float v) {
  unsigned int u = __float_as_uint(v);
  return (unsigned short)((u + 0x7FFFu + ((u >> 16) & 1u)) >> 16);
}

// ---------------- fused conv1+bn+gelu -> conv2(MFMA)+bn+gelu+pool -----------
// Grid: 2048 blocks = 1024 sensors x 2 halves of 512 positions. 256 thr.
// h1 in LDS as bf16 [516 rows][40 shorts] (32 ch + pad, 80B stride, 16B frag
// alignment). conv2 = 5 tap-shifted K=32 MFMAs per 16x16 tile.
__global__ __launch_bounds__(256) void encoder_kernel(
    const float* __restrict__ x,
    const float* __restrict__ w1, const float* __restrict__ b1,
    const float* __restrict__ g1, const float* __restrict__ be1,
    const float* __restrict__ m1, const float* __restrict__ v1,
    const float* __restrict__ w2, const float* __restrict__ b2,
    const float* __restrict__ g2, const float* __restrict__ be2,
    const float* __restrict__ m2, const float* __restrict__ v2,
    float* __restrict__ pooled)
{
  const int blk = blockIdx.x;
  const int n = blk >> 1, hb = blk & 1;
  const int P0 = hb * 512;
  const int tid = threadIdx.x;

  __shared__ __align__(16) float xs[524];
  __shared__ __align__(16) unsigned short h1s[516 * 40];

  // stage x slice: x[P0-5 .. P0+516], zero-padded
  for (int s = tid; s < 522; s += 256) {
    int gp = P0 - 5 + s;
    xs[s] = (gp >= 0 && gp < 1024) ? x[n * 1024 + gp] : 0.f;
  }

  // ---- B fragments + bn2 constants (global loads overlap conv1) ----
  const int l = tid & 63;
  const int w = tid >> 6;        // wave id = oc-tile
  const int col = l & 15;        // A-row / B-col / D-col index
  const int kh = l >> 4;         // k-group (8 bf16 each)
  const int oc = w * 16 + col;
  bf16x8 bf[5];
#pragma unroll
  for (int t = 0; t < 5; t++) {
#pragma unroll
    for (int e = 0; e < 8; e++)
      bf[t][e] = (short)to_bf16(w2[(oc * 32 + kh * 8 + e) * 5 + t]);
  }
  const float sc2 = g2[oc] * rsqrtf(v2[oc] + 1e-5f);
  const float sh2 = (b2[oc] - m2[oc]) * sc2 + be2[oc];

  // conv1 weights + bn1 for this thread's channel
  const int ch = tid & 31;
  float wk[7];
#pragma unroll
  for (int k = 0; k < 7; k++) wk[k] = w1[ch * 7 + k];
  const float s1 = g1[ch] * rsqrtf(v1[ch] + 1e-5f);
  const float t1 = (b1[ch] - m1[ch]) * s1 + be1[ch];

  __syncthreads();

  // conv1 (1->32, k=7, pad3) + bn1 + gelu -> h1 bf16 [row][ch]
  // row r covers conv2-input pos P0-2+r; rows outside [0,1024) zeroed.
  const int rb = tid >> 5;
  for (int r = rb; r < 516; r += 8) {
    float acc = 0.f;
#pragma unroll
    for (int k = 0; k < 7; k++) acc += wk[k] * xs[r + k];
    int pos = P0 - 2 + r;
    unsigned short hv = to_bf16(gelu_fast(fmaf(acc, s1, t1)));
    h1s[r * 40 + ch] = (pos >= 0 && pos < 1024) ? hv : (unsigned short)0;
  }
  __syncthreads();

  // conv2 via MFMA: D[pos16 x oc16] += sum_t A_t(16x32) * B_t(32x16)
  float pool = 0.f;
#pragma unroll 4
  for (int pt = 0; pt < 32; pt++) {
    f32x4 acc = {0.f, 0.f, 0.f, 0.f};
    const unsigned short* ap = &h1s[(pt * 16 + col) * 40 + kh * 8];
#pragma unroll
    for (int t = 0; t < 5; t++) {
      bf16x8 af = *(const bf16x8*)(ap + t * 40);
      acc = __builtin_amdgcn_mfma_f32_16x16x32_bf16(af, bf[t], acc, 0, 0, 0);
    }
    float s = 0.f;
#pragma unroll
    for (int rr = 0; rr < 4; rr++) s += gelu_fast(fmaf(acc[rr], sc2, sh2));
    pool += s;
    if ((pt & 3) == 3) {
      pool += __shfl_xor(pool, 16);
      pool += __shfl_xor(pool, 32);
      if (l < 16)
        pooled[(n * 64 + oc) * 16 + hb * 8 + (pt >> 2)] = pool * (1.f / 64.f);
      pool = 0.f;
    }
  }
}

// ---------------- generic fp32 GEMM-NT: C = act(scale*A@W^T + bias + R) -----
template<int BN, int TN, bool RELU>
__global__ __launch_bounds__(256) void gemm_nt(
    const float* __restrict__ A, int lda, int strideA,
    const float* __restrict__ W, int ldw, int strideW,
    const float* __restrict__ bias,
    const float* __restrict__ R,
    float* __restrict__ C, int ldc, long long strideC,
    int K, float scale)
{
  const int m0 = blockIdx.x * 32;
  const int n0 = blockIdx.y * BN;
  A += (size_t)blockIdx.z * strideA;
  W += (size_t)blockIdx.z * strideW;
  C += (size_t)blockIdx.z * strideC;

  __shared__ float As[32][33];
  __shared__ float Ws[32][BN + 1];
  const int tid = threadIdx.x;
  const int tm = (tid & 15) * 2;
  const int tn = (tid >> 4) * TN;
  float acc[2][TN];
#pragma unroll
  for (int i = 0; i < 2; i++)
#pragma unroll
    for (int j = 0; j < TN; j++) acc[i][j] = 0.f;

  const int ar = tid >> 3, kq = (tid & 7) * 4;
  for (int k0 = 0; k0 < K; k0 += 32) {
    float4 av = *(const float4*)(A + (size_t)(m0 + ar) * lda + k0 + kq);
    As[kq][ar] = av.x; As[kq + 1][ar] = av.y;
    As[kq + 2][ar] = av.z; As[kq + 3][ar] = av.w;
#pragma unroll
    for (int rr = 0; rr < BN / 32; rr++) {
      int r = ar + rr * 32;
      float4 wv = *(const float4*)(W + (size_t)(n0 + r) * ldw + k0 + kq);
      Ws[kq][r] = wv.x; Ws[kq + 1][r] = wv.y;
      Ws[kq + 2][r] = wv.z; Ws[kq + 3][r] = wv.w;
    }
    __syncthreads();
#pragma unroll
    for (int k = 0; k < 32; k++) {
      float a0 = As[k][tm], a1 = As[k][tm + 1];
#pragma unroll
      for (int j = 0; j < TN; j++) {
        float bv = Ws[k][tn + j];
        acc[0][j] += a0 * bv;
        acc[1][j] += a1 * bv;
      }
    }
    __syncthreads();
  }
#pragma unroll
  for (int ii = 0; ii < 2; ii++) {
    int m = m0 + tm + ii;
#pragma unroll
    for (int j = 0; j < TN; j++) {
      int nn = n0 + tn + j;
      float v = acc[ii][j] * scale;
      if (bias) v += bias[nn];
      if (R) v += R[(size_t)m * ldc + nn];
      if (RELU) v = fmaxf(v, 0.f);
      C[(size_t)m * ldc + nn] = v;
    }
  }
}

// ---------------- PV: O[i, h*32+d] = sum_j P[z,i,j] * V[j, h*32+d] ----------
__global__ __launch_bounds__(256) void pv_kernel(
    const float* __restrict__ S, const float* __restrict__ qkv,
    float* __restrict__ O, int h0)
{
  const int m0 = blockIdx.x * 32;
  const int h = h0 + blockIdx.z;
  const float* A = S + (size_t)blockIdx.z * 1024 * 1024;  // lda 1024
  const float* B = qkv + 256 + h * 32;                    // ldb 384, 32 cols
  __shared__ float As[32][33];
  __shared__ float Bs[32][33];
  const int tid = threadIdx.x;
  const int tm = (tid & 15) * 2, tn = (tid >> 4) * 2;
  float acc[2][2] = {{0.f,0.f},{0.f,0.f}};
  const int r = tid >> 3, q4 = (tid & 7) * 4;
  for (int k0 = 0; k0 < 1024; k0 += 32) {
    float4 av = *(const float4*)(A + (size_t)(m0 + r) * 1024 + k0 + q4);
    As[q4][r] = av.x; As[q4 + 1][r] = av.y; As[q4 + 2][r] = av.z; As[q4 + 3][r] = av.w;
    float4 bv = *(const float4*)(B + (size_t)(k0 + r) * 384 + q4);
    Bs[r][q4] = bv.x; Bs[r][q4 + 1] = bv.y; Bs[r][q4 + 2] = bv.z; Bs[r][q4 + 3] = bv.w;
    __syncthreads();
#pragma unroll
    for (int k = 0; k < 32; k++) {
      float a0 = As[k][tm], a1 = As[k][tm + 1];
      float b0 = Bs[k][tn], b1 = Bs[k][tn + 1];
      acc[0][0] += a0 * b0; acc[0][1] += a0 * b1;
      acc[1][0] += a1 * b0; acc[1][1] += a1 * b1;
    }
    __syncthreads();
  }
#pragma unroll
  for (int ii = 0; ii < 2; ii++)
#pragma unroll
    for (int jj = 0; jj < 2; jj++)
      O[(size_t)(m0 + tm + ii) * 128 + h * 32 + tn + jj] = acc[ii][jj];
}

// ---------------- row softmax over 1024, 4 rows per block (1 wave each) ----
__global__ __launch_bounds__(256) void softmax_kernel(float* __restrict__ S)
{
  int row = blockIdx.x * 4 + (threadIdx.x >> 6);
  int lane = threadIdx.x & 63;
  float* p = S + (size_t)row * 1024 + lane * 4;
  float4 v[4];
  float mx = -3.4e38f;
#pragma unroll
  for (int j = 0; j < 4; j++) {
    v[j] = *(float4*)(p + j * 256);
    mx = fmaxf(mx, fmaxf(fmaxf(v[j].x, v[j].y), fmaxf(v[j].z, v[j].w)));
  }
#pragma unroll
  for (int off = 32; off >= 1; off >>= 1) mx = fmaxf(mx, __shfl_xor(mx, off));
  float sum = 0.f;
#pragma unroll
  for (int j = 0; j < 4; j++) {
    v[j].x = __expf(v[j].x - mx); v[j].y = __expf(v[j].y - mx);
    v[j].z = __expf(v[j].z - mx); v[j].w = __expf(v[j].w - mx);
    sum += v[j].x + v[j].y + v[j].z + v[j].w;
  }
#pragma unroll
  for (int off = 32; off >= 1; off >>= 1) sum += __shfl_xor(sum, off);
  float inv = 1.f / sum;
#pragma unroll
  for (int j = 0; j < 4; j++) {
    v[j].x *= inv; v[j].y *= inv; v[j].z *= inv; v[j].w *= inv;
    *(float4*)(p + j * 256) = v[j];
  }
}

// ---------------- LayerNorm(128) in place, 4 rows/block -------------------
__global__ __launch_bounds__(256) void ln_kernel(
    float* __restrict__ t, const float* __restrict__ g, const float* __restrict__ b)
{
  int row = blockIdx.x * 4 + (threadIdx.x >> 6);
  int lane = threadIdx.x & 63;
  float* p = t + (size_t)row * 128 + lane * 2;
  float2 v = *(float2*)p;
  float s = v.x + v.y;
#pragma unroll
  for (int off = 32; off >= 1; off >>= 1) s += __shfl_xor(s, off);
  float mu = s * (1.f / 128.f);
  float dx = v.x - mu, dy = v.y - mu;
  float q = dx * dx + dy * dy;
#pragma unroll
  for (int off = 32; off >= 1; off >>= 1) q += __shfl_xor(q, off);
  float inv = rsqrtf(q * (1.f / 128.f) + 1e-5f);
  float2 gv = *(const float2*)(g + lane * 2);
  float2 bv = *(const float2*)(b + lane * 2);
  float2 o = make_float2(dx * inv * gv.x + bv.x, dy * inv * gv.y + bv.y);
  *(float2*)p = o;
}

// ---------------- node head second layer (N=3) -----------------------------
__global__ __launch_bounds__(256) void nh2_kernel(
    const float* __restrict__ mid, const float* __restrict__ w,
    const float* __restrict__ b, float* __restrict__ out)
{
  int m = blockIdx.x * 256 + threadIdx.x;   // 1024 rows
  const float* row = mid + (size_t)m * 128;
  float a0 = 0.f, a1 = 0.f, a2 = 0.f;
#pragma unroll 4
  for (int k = 0; k < 128; k++) {
    float xv = row[k];
    a0 += xv * w[k]; a1 += xv * w[128 + k]; a2 += xv * w[256 + k];
  }
  out[m * 3 + 0] = a0 + b[0];
  out[m * 3 + 1] = a1 + b[1];
  out[m * 3 + 2] = a2 + b[2];
}

// ---------------- all-pairs edge: out[i,j] = relu(hi[i]+hjb[j]).w + e2b ----
__global__ __launch_bounds__(256) void edge_kernel(
    const float* __restrict__ hi, const float* __restrict__ hjb,
    const float* __restrict__ w, const float* __restrict__ e2b,
    float* __restrict__ out)
{
  const int i0 = blockIdx.x * 64;
  const int j0 = blockIdx.y * 32;
  __shared__ float his[128][64];
  __shared__ float hjs[128][32];
  const int tid = threadIdx.x;
  {
    int r = tid >> 2, c0 = (tid & 3) * 32;
#pragma unroll
    for (int u = 0; u < 8; u++) {
      float4 v = *(const float4*)(hi + (size_t)(i0 + r) * 128 + c0 + u * 4);
      his[c0 + u * 4 + 0][r] = v.x; his[c0 + u * 4 + 1][r] = v.y;
      his[c0 + u * 4 + 2][r] = v.z; his[c0 + u * 4 + 3][r] = v.w;
    }
  }
  {
    int r = tid >> 3, c0 = (tid & 7) * 16;
#pragma unroll
    for (int u = 0; u < 4; u++) {
      float4 v = *(const float4*)(hjb + (size_t)(j0 + r) * 128 + c0 + u * 4);
      hjs[c0 + u * 4 + 0][r] = v.x; hjs[c0 + u * 4 + 1][r] = v.y;
      hjs[c0 + u * 4 + 2][r] = v.z; hjs[c0 + u * 4 + 3][r] = v.w;
    }
  }
  __syncthreads();
  const int il = (tid & 15) * 4, jl = (tid >> 4) * 2;
  float acc[4][2] = {{0.f,0.f},{0.f,0.f},{0.f,0.f},{0.f,0.f}};
  for (int e = 0; e < 128; e++) {
    float4 a = *(const float4*)&his[e][il];
    float2 bv = *(const float2*)&hjs[e][jl];
    float we = w[e];
    float av[4] = {a.x, a.y, a.z, a.w};
    float bb[2] = {bv.x, bv.y};
#pragma unroll
    for (int ii = 0; ii < 4; ii++)
#pragma unroll
      for (int jj = 0; jj < 2; jj++)
        acc[ii][jj] += fmaxf(av[ii] + bb[jj], 0.f) * we;
  }
  float eb = e2b[0];
#pragma unroll
  for (int ii = 0; ii < 4; ii++) {
    float2 vv = make_float2(acc[ii][0] + eb, acc[ii][1] + eb);
    *(float2*)(out + (size_t)(i0 + il + ii) * 1024 + j0 + jl) = vv;
  }
}

// ---------------------------------------------------------------------------
extern "C" void kernel_launch(void* const* d_in, const int* in_sizes, int n_in,
                              void* d_out, int out_size, void* d_ws, size_t ws_size,
                              hipStream_t stream)
{
  const float* x        = (const float*)d_in[0];
  const float* conv1_w  = (const float*)d_in[1];
  const float* conv1_b  = (const float*)d_in[2];
  const float* bn1_g    = (const float*)d_in[3];
  const float* bn1_b    = (const float*)d_in[4];
  const float* bn1_m    = (const float*)d_in[5];
  const float* bn1_v    = (const float*)d_in[6];
  const float* conv2_w  = (const float*)d_in[7];
  const float* conv2_b  = (const float*)d_in[8];
  const float* bn2_g    = (const float*)d_in[9];
  const float* bn2_b    = (const float*)d_in[10];
  const float* bn2_m    = (const float*)d_in[11];
  const float* bn2_v    = (const float*)d_in[12];
  const float* proj_w   = (const float*)d_in[13];
  const float* proj_b   = (const float*)d_in[14];
  const float* attn_in_w  = (const float*)d_in[15];
  const float* attn_in_b  = (const float*)d_in[16];
  const float* attn_out_w = (const float*)d_in[17];
  const float* attn_out_b = (const float*)d_in[18];
  const float* ln1_g    = (const float*)d_in[19];
  const float* ln1_b    = (const float*)d_in[20];
  const float* ff1_w    = (const float*)d_in[21];
  const float* ff1_b    = (const float*)d_in[22];
  const float* ff2_w    = (const float*)d_in[23];
  const float* ff2_b    = (const float*)d_in[24];
  const float* ln2_g    = (const float*)d_in[25];
  const float* ln2_b    = (const float*)d_in[26];
  const float* nh1_w    = (const float*)d_in[27];
  const float* nh1_b    = (const float*)d_in[28];
  const float* nh2_w    = (const float*)d_in[29];
  const float* nh2_b    = (const float*)d_in[30];
  const float* e1_w     = (const float*)d_in[31];
  const float* e1_b     = (const float*)d_in[32];
  const float* e2_w     = (const float*)d_in[33];
  const float* e2_b     = (const float*)d_in[34];
  const float* p1_w     = (const float*)d_in[35];
  const float* p1_b     = (const float*)d_in[36];
  const float* p2_w     = (const float*)d_in[37];
  const float* p2_b     = (const float*)d_in[38];

  float* ws = (float*)d_ws;

  // Two arena layouts, chosen by actual ws_size (host-side, deterministic).
  const bool full = (ws_size >= (size_t)5636096 * 4);
  const size_t RN = full ? 4194304 : 1048576;
  float* R      = ws;                  // pooled / Sbuf / fbuf share this
  float* z      = ws + RN;
  float* tA     = z + 131072;
  float* tB     = tA + 131072;
  float* qkvb   = tB + 131072;         // 1024*384
  float* attnO  = qkvb + 393216;
  float* hib    = attnO + 131072;
  float* hjbb   = hib + 131072;
  float* nhmid  = hjbb + 131072;
  float* pmid   = nhmid + 131072;

  float* pooled = R;                   // 1024*1024 (both layouts)
  float* Sbuf   = R;                   // full: 4 heads; compact: 1 head
  float* fbuf   = R;                   // full: 1024*2048; compact: 1024*1024

  float* out_node = (float*)d_out;
  float* out_edge = out_node + 3072;
  float* out_proj = out_edge + 1048576;

  const float iso = 0.17677669529663689f;  // 1/sqrt(32)

  // ---- sensor temporal encoder (fused, conv2 via bf16 MFMA) ----
  encoder_kernel<<<2048, 256, 0, stream>>>(
      x, conv1_w, conv1_b, bn1_g, bn1_b, bn1_m, bn1_v,
      conv2_w, conv2_b, bn2_g, bn2_b, bn2_m, bn2_v, pooled);

  // z = pooled @ proj_w^T + proj_b
  gemm_nt<32, 2, false><<<dim3(32, 4, 1), 256, 0, stream>>>(
      pooled, 1024, 0, proj_w, 1024, 0, proj_b, nullptr, z, 128, 0, 1024, 1.f);

  // ---- transformer layers ----
  for (int l = 0; l < 2; l++) {
    const float* tIn = l ? tA : z;
    gemm_nt<32, 2, false><<<dim3(32, 12, 1), 256, 0, stream>>>(
        tIn, 128, 0, attn_in_w + l * 384 * 128, 128, 0,
        attn_in_b + l * 384, nullptr, qkvb, 384, 0, 128, 1.f);

    if (full) {
      gemm_nt<32, 2, false><<<dim3(32, 32, 4), 256, 0, stream>>>(
          qkvb, 384, 32, qkvb + 128, 384, 32, nullptr, nullptr,
          Sbuf, 1024, 1048576LL, 32, iso);
      softmax_kernel<<<1024, 256, 0, stream>>>(Sbuf);
      pv_kernel<<<dim3(32, 1, 4), 256, 0, stream>>>(Sbuf, qkvb, attnO, 0);
    } else {
      for (int h = 0; h < 4; h++) {
        gemm_nt<32, 2, false><<<dim3(32, 32, 1), 256, 0, stream>>>(
            qkvb + h * 32, 384, 0, qkvb + 128 + h * 32, 384, 0,
            nullptr, nullptr, Sbuf, 1024, 0, 32, iso);
        softmax_kernel<<<256, 256, 0, stream>>>(Sbuf);
        pv_kernel<<<dim3(32, 1, 1), 256, 0, stream>>>(Sbuf, qkvb, attnO, h);
      }
    }

    // pre1 = tIn + attnO @ Wo^T + bo
    gemm_nt<32, 2, false><<<dim3(32, 4, 1), 256, 0, stream>>>(
        attnO, 128, 0, attn_out_w + l * 128 * 128, 128, 0,
        attn_out_b + l * 128, tIn, tB, 128, 0, 128, 1.f);
    ln_kernel<<<256, 256, 0, stream>>>(tB, ln1_g + l * 128, ln1_b + l * 128);

    if (full) {
      gemm_nt<64, 4, true><<<dim3(32, 32, 1), 256, 0, stream>>>(
          tB, 128, 0, ff1_w + l * 2048 * 128, 128, 0,
          ff1_b + l * 2048, nullptr, fbuf, 2048, 0, 128, 1.f);
      gemm_nt<32, 2, false><<<dim3(32, 4, 1), 256, 0, stream>>>(
          fbuf, 2048, 0, ff2_w + l * 128 * 2048, 2048, 0,
          ff2_b + l * 128, tB, tA, 128, 0, 2048, 1.f);
    } else {
      gemm_nt<64, 4, true><<<dim3(32, 16, 1), 256, 0, stream>>>(
          tB, 128, 0, ff1_w + l * 2048 * 128, 128, 0,
          ff1_b + l * 2048, nullptr, fbuf, 1024, 0, 128, 1.f);
      gemm_nt<32, 2, false><<<dim3(32, 4, 1), 256, 0, stream>>>(
          fbuf, 1024, 0, ff2_w + l * 128 * 2048, 2048, 0,
          ff2_b + l * 128, tB, tA, 128, 0, 1024, 1.f);
      gemm_nt<64, 4, true><<<dim3(32, 16, 1), 256, 0, stream>>>(
          tB, 128, 0, ff1_w + l * 2048 * 128 + 1024 * 128, 128, 0,
          ff1_b + l * 2048 + 1024, nullptr, fbuf, 1024, 0, 128, 1.f);
      gemm_nt<32, 2, false><<<dim3(32, 4, 1), 256, 0, stream>>>(
          fbuf, 1024, 0, ff2_w + l * 128 * 2048 + 1024, 2048, 0,
          nullptr, tA, tA, 128, 0, 1024, 1.f);
    }
    ln_kernel<<<256, 256, 0, stream>>>(tA, ln2_g + l * 128, ln2_b + l * 128);
  }

  // ---- node head ----
  gemm_nt<32, 2, true><<<dim3(32, 4, 1), 256, 0, stream>>>(
      tA, 128, 0, nh1_w, 128, 0, nh1_b, nullptr, nhmid, 128, 0, 128, 1.f);
  nh2_kernel<<<4, 256, 0, stream>>>(nhmid, nh2_w, nh2_b, out_node);

  // ---- edge MLP ----
  gemm_nt<32, 2, false><<<dim3(32, 4, 1), 256, 0, stream>>>(
      tA, 128, 0, e1_w, 256, 0, nullptr, nullptr, hib, 128, 0, 128, 1.f);
  gemm_nt<32, 2, false><<<dim3(32, 4, 1), 256, 0, stream>>>(
      tA, 128, 0, e1_w + 128, 256, 0, e1_b, nullptr, hjbb, 128, 0, 128, 1.f);
  edge_kernel<<<dim3(16, 32), 256, 0, stream>>>(hib, hjbb, e2_w, e2_b, out_edge);

  // ---- projector (on z) ----
  gemm_nt<32, 2, true><<<dim3(32, 4, 1), 256, 0, stream>>>(
      z, 128, 0, p1_w, 128, 0, p1_b, nullptr, pmid, 128, 0, 128, 1.f);
  gemm_nt<32, 2, false><<<dim3(32, 4, 1), 256, 0, stream>>>(
      pmid, 128, 0, p2_w, 128, 0, p2_b, nullptr, out_proj, 128, 0, 128, 1.f);
}

// Round 5
// 492.308 us; speedup vs baseline: 2.2355x; 1.2376x over previous
//
#include <hip/hip_runtime.h>
#include <math.h>

// ---------------------------------------------------------------------------
// TypeGraphModel: conv encoder (bf16 MFMA) + bf16-MFMA transformer + heads.
// N=1024, D=1024, CC=64, TP=16, EMB=128, NH=4, HD=32, L=2, FF=2048
// ---------------------------------------------------------------------------

typedef float f32x4 __attribute__((ext_vector_type(4)));
typedef short bf16x8 __attribute__((ext_vector_type(8)));
typedef unsigned short u16;
typedef unsigned short us4 __attribute__((ext_vector_type(4)));

// Abramowitz-Stegun 7.1.26 erf (max abs err 1.5e-7) -> exact-GELU
__device__ __forceinline__ float gelu_fast(float v) {
  float ax = fabsf(v) * 0.70710678118654752440f;
  float t = __builtin_amdgcn_rcpf(fmaf(0.3275911f, ax, 1.f));
  float p = fmaf(1.061405429f, t, -1.453152027f);
  p = fmaf(p, t, 1.421413741f);
  p = fmaf(p, t, -0.284496736f);
  p = fmaf(p, t, 0.254829592f);
  p = p * t;
  float e = __expf(-ax * ax);
  float erfa = fmaf(-p, e, 1.f);
  float erfv = copysignf(erfa, v);
  return 0.5f * v * (1.f + erfv);
}

__device__ __forceinline__ u16 to_bf16(float v) {
  unsigned int u = __float_as_uint(v);
  return (u16)((u + 0x7FFFu + ((u >> 16) & 1u)) >> 16);
}

// ---------------- fused conv1+bn+gelu -> conv2(MFMA)+bn+gelu+pool -----------
// Grid: 2048 blocks = 1024 sensors x 2 halves of 512 positions. 256 thr.
__global__ __launch_bounds__(256) void encoder_kernel(
    const float* __restrict__ x,
    const float* __restrict__ w1, const float* __restrict__ b1,
    const float* __restrict__ g1, const float* __restrict__ be1,
    const float* __restrict__ m1, const float* __restrict__ v1,
    const float* __restrict__ w2, const float* __restrict__ b2,
    const float* __restrict__ g2, const float* __restrict__ be2,
    const float* __restrict__ m2, const float* __restrict__ v2,
    u16* __restrict__ pooled_bf)
{
  const int blk = blockIdx.x;
  const int n = blk >> 1, hb = blk & 1;
  const int P0 = hb * 512;
  const int tid = threadIdx.x;

  __shared__ __align__(16) float xs[524];
  __shared__ __align__(16) u16 h1s[516 * 40];

  for (int s = tid; s < 522; s += 256) {
    int gp = P0 - 5 + s;
    xs[s] = (gp >= 0 && gp < 1024) ? x[n * 1024 + gp] : 0.f;
  }

  const int l = tid & 63;
  const int w = tid >> 6;        // wave id = oc-tile
  const int col = l & 15;
  const int kh = l >> 4;
  const int oc = w * 16 + col;
  bf16x8 bf[5];
#pragma unroll
  for (int t = 0; t < 5; t++) {
#pragma unroll
    for (int e = 0; e < 8; e++)
      bf[t][e] = (short)to_bf16(w2[(oc * 32 + kh * 8 + e) * 5 + t]);
  }
  const float sc2 = g2[oc] * rsqrtf(v2[oc] + 1e-5f);
  const float sh2 = (b2[oc] - m2[oc]) * sc2 + be2[oc];

  const int ch = tid & 31;
  float wk[7];
#pragma unroll
  for (int k = 0; k < 7; k++) wk[k] = w1[ch * 7 + k];
  const float s1 = g1[ch] * rsqrtf(v1[ch] + 1e-5f);
  const float t1 = (b1[ch] - m1[ch]) * s1 + be1[ch];

  __syncthreads();

  const int rb = tid >> 5;
  for (int r = rb; r < 516; r += 8) {
    float acc = 0.f;
#pragma unroll
    for (int k = 0; k < 7; k++) acc += wk[k] * xs[r + k];
    int pos = P0 - 2 + r;
    u16 hv = to_bf16(gelu_fast(fmaf(acc, s1, t1)));
    h1s[r * 40 + ch] = (pos >= 0 && pos < 1024) ? hv : (u16)0;
  }
  __syncthreads();

  float pool = 0.f;
#pragma unroll 4
  for (int pt = 0; pt < 32; pt++) {
    f32x4 acc = {0.f, 0.f, 0.f, 0.f};
    const u16* ap = &h1s[(pt * 16 + col) * 40 + kh * 8];
#pragma unroll
    for (int t = 0; t < 5; t++) {
      bf16x8 af = *(const bf16x8*)(ap + t * 40);
      acc = __builtin_amdgcn_mfma_f32_16x16x32_bf16(af, bf[t], acc, 0, 0, 0);
    }
    float s = 0.f;
#pragma unroll
    for (int rr = 0; rr < 4; rr++) s += gelu_fast(fmaf(acc[rr], sc2, sh2));
    pool += s;
    if ((pt & 3) == 3) {
      pool += __shfl_xor(pool, 16);
      pool += __shfl_xor(pool, 32);
      if (l < 16)
        pooled_bf[(n * 64 + oc) * 16 + hb * 8 + (pt >> 2)] =
            to_bf16(pool * (1.f / 64.f));
      pool = 0.f;
    }
  }
}

// ---------------- universal bf16 MFMA GEMM-NT --------------------------------
// D[m,n] = scale * sum_k A[m,k]*B[n,k] (+bias[n]) (+Res[m*ldc+n]) (relu)
// A bf16 (K-contig rows). B: f32 (packed in-reg) or bf16, K-contig rows.
// 1 wave/block; tile 32(M) x NR*16(N). Epilogue: Cf f32 / Cb bf16 / VT scatter.
template<int NR, bool BF32, bool RELU, bool VT>
__global__ __launch_bounds__(64) void mm_kernel(
    const u16* __restrict__ A, int lda, long long zA,
    const void* __restrict__ Bv, int ldb, long long zB,
    const float* __restrict__ bias,
    const float* __restrict__ Res,
    float* __restrict__ Cf, u16* __restrict__ Cb, u16* __restrict__ vt,
    int ldc, long long zC, int K, float scale)
{
  const int z = blockIdx.z;
  const int m0 = blockIdx.x * 32, n0 = blockIdx.y * (NR * 16);
  const int l = threadIdx.x;
  const int r = l & 15, kh = l >> 4;

  A += (size_t)z * zA;
  f32x4 acc[2][NR];
#pragma unroll
  for (int i = 0; i < 2; i++)
#pragma unroll
    for (int j = 0; j < NR; j++) acc[i][j] = (f32x4){0.f, 0.f, 0.f, 0.f};

  const u16* Ap0 = A + (size_t)(m0 + r) * lda + kh * 8;
  const u16* Ap1 = Ap0 + (size_t)16 * lda;
  const float* Bf = (const float*)Bv + (BF32 ? (size_t)z * zB + (size_t)(n0 + r) * ldb + kh * 8 : 0);
  const u16*  Bb = (const u16*)Bv  + (BF32 ? 0 : (size_t)z * zB + (size_t)(n0 + r) * ldb + kh * 8);

  for (int k0 = 0; k0 < K; k0 += 32) {
    bf16x8 a0 = *(const bf16x8*)(Ap0 + k0);
    bf16x8 a1 = *(const bf16x8*)(Ap1 + k0);
    bf16x8 bfr[NR];
#pragma unroll
    for (int ni = 0; ni < NR; ni++) {
      if (BF32) {
        const float* bp = Bf + (size_t)ni * 16 * ldb + k0;
        float4 w0 = *(const float4*)bp;
        float4 w1 = *(const float4*)(bp + 4);
        bfr[ni][0] = (short)to_bf16(w0.x); bfr[ni][1] = (short)to_bf16(w0.y);
        bfr[ni][2] = (short)to_bf16(w0.z); bfr[ni][3] = (short)to_bf16(w0.w);
        bfr[ni][4] = (short)to_bf16(w1.x); bfr[ni][5] = (short)to_bf16(w1.y);
        bfr[ni][6] = (short)to_bf16(w1.z); bfr[ni][7] = (short)to_bf16(w1.w);
      } else {
        bfr[ni] = *(const bf16x8*)(Bb + (size_t)ni * 16 * ldb + k0);
      }
    }
#pragma unroll
    for (int ni = 0; ni < NR; ni++) {
      acc[0][ni] = __builtin_amdgcn_mfma_f32_16x16x32_bf16(a0, bfr[ni], acc[0][ni], 0, 0, 0);
      acc[1][ni] = __builtin_amdgcn_mfma_f32_16x16x32_bf16(a1, bfr[ni], acc[1][ni], 0, 0, 0);
    }
  }

  if (Cf) Cf += (size_t)z * zC;
  if (Cb) Cb += (size_t)z * zC;
#pragma unroll
  for (int mi = 0; mi < 2; mi++) {
#pragma unroll
    for (int ni = 0; ni < NR; ni++) {
#pragma unroll
      for (int reg = 0; reg < 4; reg++) {
        int row = m0 + mi * 16 + kh * 4 + reg;
        int colx = n0 + ni * 16 + r;
        float v = acc[mi][ni][reg] * scale;
        if (bias) v += bias[colx];
        if (Res) v += Res[(size_t)row * ldc + colx];
        if (RELU) v = fmaxf(v, 0.f);
        if (Cf) Cf[(size_t)row * ldc + colx] = v;
        if (Cb) Cb[(size_t)row * ldc + colx] = to_bf16(v);
        if (VT) {
          if (colx >= 256) {
            int hv = (colx - 256) >> 5, dv = (colx - 256) & 31;
            vt[(size_t)hv * 32768 + (size_t)dv * 1024 + row] = to_bf16(v);
          }
        }
      }
    }
  }
}

// ---------------- row softmax over 1024 f32 -> bf16 P in place -------------
__global__ __launch_bounds__(256) void softmax_kernel(float* __restrict__ S)
{
  int row = blockIdx.x * 4 + (threadIdx.x >> 6);
  int lane = threadIdx.x & 63;
  float* p = S + (size_t)row * 1024 + lane * 4;
  float4 v[4];
  float mx = -3.4e38f;
#pragma unroll
  for (int j = 0; j < 4; j++) {
    v[j] = *(float4*)(p + j * 256);
    mx = fmaxf(mx, fmaxf(fmaxf(v[j].x, v[j].y), fmaxf(v[j].z, v[j].w)));
  }
#pragma unroll
  for (int off = 32; off >= 1; off >>= 1) mx = fmaxf(mx, __shfl_xor(mx, off));
  float sum = 0.f;
#pragma unroll
  for (int j = 0; j < 4; j++) {
    v[j].x = __expf(v[j].x - mx); v[j].y = __expf(v[j].y - mx);
    v[j].z = __expf(v[j].z - mx); v[j].w = __expf(v[j].w - mx);
    sum += v[j].x + v[j].y + v[j].z + v[j].w;
  }
#pragma unroll
  for (int off = 32; off >= 1; off >>= 1) sum += __shfl_xor(sum, off);
  float inv = 1.f / sum;
  u16* q = (u16*)S + (size_t)row * 2048;
#pragma unroll
  for (int j = 0; j < 4; j++) {
    us4 o;
    o[0] = to_bf16(v[j].x * inv); o[1] = to_bf16(v[j].y * inv);
    o[2] = to_bf16(v[j].z * inv); o[3] = to_bf16(v[j].w * inv);
    *(us4*)(q + lane * 4 + j * 256) = o;
  }
}

// ---------------- LayerNorm(128): pre f32 -> t f32 + t bf16 ---------------
__global__ __launch_bounds__(256) void ln_kernel(
    const float* __restrict__ in, float* __restrict__ out, u16* __restrict__ outb,
    const float* __restrict__ g, const float* __restrict__ b)
{
  int row = blockIdx.x * 4 + (threadIdx.x >> 6);
  int lane = threadIdx.x & 63;
  const float* p = in + (size_t)row * 128 + lane * 2;
  float2 v = *(const float2*)p;
  float s = v.x + v.y;
#pragma unroll
  for (int off = 32; off >= 1; off >>= 1) s += __shfl_xor(s, off);
  float mu = s * (1.f / 128.f);
  float dx = v.x - mu, dy = v.y - mu;
  float q = dx * dx + dy * dy;
#pragma unroll
  for (int off = 32; off >= 1; off >>= 1) q += __shfl_xor(q, off);
  float inv = rsqrtf(q * (1.f / 128.f) + 1e-5f);
  float2 gv = *(const float2*)(g + lane * 2);
  float2 bv = *(const float2*)(b + lane * 2);
  float ox = dx * inv * gv.x + bv.x, oy = dy * inv * gv.y + bv.y;
  size_t idx = (size_t)row * 128 + lane * 2;
  out[idx] = ox; out[idx + 1] = oy;
  outb[idx] = to_bf16(ox); outb[idx + 1] = to_bf16(oy);
}

// ---------------- node head second layer (N=3) -----------------------------
__global__ __launch_bounds__(256) void nh2_kernel(
    const float* __restrict__ mid, const float* __restrict__ w,
    const float* __restrict__ b, float* __restrict__ out)
{
  int m = blockIdx.x * 256 + threadIdx.x;
  const float* row = mid + (size_t)m * 128;
  float a0 = 0.f, a1 = 0.f, a2 = 0.f;
#pragma unroll 4
  for (int k = 0; k < 128; k++) {
    float xv = row[k];
    a0 += xv * w[k]; a1 += xv * w[128 + k]; a2 += xv * w[256 + k];
  }
  out[m * 3 + 0] = a0 + b[0];
  out[m * 3 + 1] = a1 + b[1];
  out[m * 3 + 2] = a2 + b[2];
}

// ---------------- all-pairs edge: out[i,j] = relu(hi[i]+hjb[j]).w + e2b ----
__global__ __launch_bounds__(256) void edge_kernel(
    const float* __restrict__ hi, const float* __restrict__ hjb,
    const float* __restrict__ w, const float* __restrict__ e2b,
    float* __restrict__ out)
{
  const int i0 = blockIdx.x * 64;
  const int j0 = blockIdx.y * 32;
  __shared__ float his[128][64];
  __shared__ float hjs[128][32];
  const int tid = threadIdx.x;
  {
    int r = tid >> 2, c0 = (tid & 3) * 32;
#pragma unroll
    for (int u = 0; u < 8; u++) {
      float4 v = *(const float4*)(hi + (size_t)(i0 + r) * 128 + c0 + u * 4);
      his[c0 + u * 4 + 0][r] = v.x; his[c0 + u * 4 + 1][r] = v.y;
      his[c0 + u * 4 + 2][r] = v.z; his[c0 + u * 4 + 3][r] = v.w;
    }
  }
  {
    int r = tid >> 3, c0 = (tid & 7) * 16;
#pragma unroll
    for (int u = 0; u < 4; u++) {
      float4 v = *(const float4*)(hjb + (size_t)(j0 + r) * 128 + c0 + u * 4);
      hjs[c0 + u * 4 + 0][r] = v.x; hjs[c0 + u * 4 + 1][r] = v.y;
      hjs[c0 + u * 4 + 2][r] = v.z; hjs[c0 + u * 4 + 3][r] = v.w;
    }
  }
  __syncthreads();
  const int il = (tid & 15) * 4, jl = (tid >> 4) * 2;
  float acc[4][2] = {{0.f,0.f},{0.f,0.f},{0.f,0.f},{0.f,0.f}};
  for (int e = 0; e < 128; e++) {
    float4 a = *(const float4*)&his[e][il];
    float2 bv = *(const float2*)&hjs[e][jl];
    float we = w[e];
    float av[4] = {a.x, a.y, a.z, a.w};
    float bb[2] = {bv.x, bv.y};
#pragma unroll
    for (int ii = 0; ii < 4; ii++)
#pragma unroll
      for (int jj = 0; jj < 2; jj++)
        acc[ii][jj] += fmaxf(av[ii] + bb[jj], 0.f) * we;
  }
  float eb = e2b[0];
#pragma unroll
  for (int ii = 0; ii < 4; ii++) {
    float2 vv = make_float2(acc[ii][0] + eb, acc[ii][1] + eb);
    *(float2*)(out + (size_t)(i0 + il + ii) * 1024 + j0 + jl) = vv;
  }
}

// ---------------------------------------------------------------------------
extern "C" void kernel_launch(void* const* d_in, const int* in_sizes, int n_in,
                              void* d_out, int out_size, void* d_ws, size_t ws_size,
                              hipStream_t stream)
{
  const float* x        = (const float*)d_in[0];
  const float* conv1_w  = (const float*)d_in[1];
  const float* conv1_b  = (const float*)d_in[2];
  const float* bn1_g    = (const float*)d_in[3];
  const float* bn1_b    = (const float*)d_in[4];
  const float* bn1_m    = (const float*)d_in[5];
  const float* bn1_v    = (const float*)d_in[6];
  const float* conv2_w  = (const float*)d_in[7];
  const float* conv2_b  = (const float*)d_in[8];
  const float* bn2_g    = (const float*)d_in[9];
  const float* bn2_b    = (const float*)d_in[10];
  const float* bn2_m    = (const float*)d_in[11];
  const float* bn2_v    = (const float*)d_in[12];
  const float* proj_w   = (const float*)d_in[13];
  const float* proj_b   = (const float*)d_in[14];
  const float* attn_in_w  = (const float*)d_in[15];
  const float* attn_in_b  = (const float*)d_in[16];
  const float* attn_out_w = (const float*)d_in[17];
  const float* attn_out_b = (const float*)d_in[18];
  const float* ln1_g    = (const float*)d_in[19];
  const float* ln1_b    = (const float*)d_in[20];
  const float* ff1_w    = (const float*)d_in[21];
  const float* ff1_b    = (const float*)d_in[22];
  const float* ff2_w    = (const float*)d_in[23];
  const float* ff2_b    = (const float*)d_in[24];
  const float* ln2_g    = (const float*)d_in[25];
  const float* ln2_b    = (const float*)d_in[26];
  const float* nh1_w    = (const float*)d_in[27];
  const float* nh1_b    = (const float*)d_in[28];
  const float* nh2_w    = (const float*)d_in[29];
  const float* nh2_b    = (const float*)d_in[30];
  const float* e1_w     = (const float*)d_in[31];
  const float* e1_b     = (const float*)d_in[32];
  const float* e2_w     = (const float*)d_in[33];
  const float* e2_b     = (const float*)d_in[34];
  const float* p1_w     = (const float*)d_in[35];
  const float* p1_b     = (const float*)d_in[36];
  const float* p2_w     = (const float*)d_in[37];
  const float* p2_b     = (const float*)d_in[38];

  float* ws = (float*)d_ws;

  // Layouts (f32 units). FULL: R=4M f32 (S 4 heads). COMPACT: R=1M (per-head S).
  // R also time-shares: pooled_bf -> S/P -> f_bf -> head buffers.
  const bool full = (ws_size >= (size_t)20 * 1024 * 1024);
  const size_t RN = full ? 4194304 : 1048576;
  float* R     = ws;
  float* z     = ws + RN;
  u16*  z_bf   = (u16*)(z + 131072);
  float* tS    = z + 131072 + 65536;
  u16*  t_bf   = (u16*)(tS + 131072);
  float* pre   = tS + 131072 + 65536;
  u16*  qkv_bf = (u16*)(pre + 131072);       // 1024x384
  u16*  vt     = qkv_bf + 393216;            // [4][32][1024]
  u16*  attnO  = vt + 131072;                // 1024x128
  // aliases into R:
  u16*  pooled_bf = (u16*)R;                 // 1024x1024 bf16
  float* Sb    = R;                          // S f32 (4 heads full / 1 compact)
  u16*  fb     = (u16*)R;                    // ff1 out 1024x2048 bf16
  float* hib   = R;                          // heads phase
  float* hjbb  = R + 131072;
  float* nhmid = R + 262144;
  u16*  pmid   = (u16*)(R + 393216);

  float* out_node = (float*)d_out;
  float* out_edge = out_node + 3072;
  float* out_proj = out_edge + 1048576;

  const float iso = 0.17677669529663689f;  // 1/sqrt(32)
  float* nullf = nullptr; u16* nullb = nullptr;

  // ---- encoder -> pooled bf16 ----
  encoder_kernel<<<2048, 256, 0, stream>>>(
      x, conv1_w, conv1_b, bn1_g, bn1_b, bn1_m, bn1_v,
      conv2_w, conv2_b, bn2_g, bn2_b, bn2_m, bn2_v, pooled_bf);

  // z = pooled @ proj_w^T + proj_b  (f32 + bf16 out)
  // NR=2 -> 32-col N-tile; EMB=128 needs grid.y=4 (R4 bug: was 2).
  mm_kernel<2, true, false, false><<<dim3(32, 4), 64, 0, stream>>>(
      pooled_bf, 1024, 0, proj_w, 1024, 0, proj_b, nullf,
      z, z_bf, nullb, 128, 0, 1024, 1.f);

  for (int l = 0; l < 2; l++) {
    const float* tin = l ? tS : z;
    const u16* tin_bf = l ? t_bf : z_bf;
    // qkv (+ V-transpose scatter into vt)
    mm_kernel<4, true, false, true><<<dim3(32, 6), 64, 0, stream>>>(
        tin_bf, 128, 0, attn_in_w + l * 49152, 128, 0, attn_in_b + l * 384,
        nullf, nullf, qkv_bf, vt, 384, 0, 128, 1.f);

    if (full) {
      mm_kernel<4, false, false, false><<<dim3(32, 16, 4), 64, 0, stream>>>(
          qkv_bf, 384, 32, qkv_bf + 128, 384, 32, nullf, nullf,
          Sb, nullb, nullb, 1024, 1048576LL, 32, iso);
      softmax_kernel<<<1024, 256, 0, stream>>>(Sb);
      mm_kernel<2, false, false, false><<<dim3(32, 1, 4), 64, 0, stream>>>(
          (const u16*)Sb, 2048, 2097152LL, vt, 1024, 32768LL, nullf, nullf,
          nullf, attnO, nullb, 128, 32LL, 1024, 1.f);
    } else {
      for (int h = 0; h < 4; h++) {
        mm_kernel<4, false, false, false><<<dim3(32, 16, 1), 64, 0, stream>>>(
            qkv_bf + h * 32, 384, 0, qkv_bf + 128 + h * 32, 384, 0,
            nullf, nullf, Sb, nullb, nullb, 1024, 0, 32, iso);
        softmax_kernel<<<256, 256, 0, stream>>>(Sb);
        mm_kernel<2, false, false, false><<<dim3(32, 1, 1), 64, 0, stream>>>(
            (const u16*)Sb, 2048, 0, vt + h * 32768, 1024, 0, nullf, nullf,
            nullf, attnO + h * 32, nullb, 128, 0, 1024, 1.f);
      }
    }

    // pre = tin + attnO @ Wo^T + bo ; ln1 -> t
    mm_kernel<2, true, false, false><<<dim3(32, 4), 64, 0, stream>>>(
        attnO, 128, 0, attn_out_w + l * 16384, 128, 0, attn_out_b + l * 128,
        tin, pre, nullb, nullb, 128, 0, 128, 1.f);
    ln_kernel<<<256, 256, 0, stream>>>(pre, tS, t_bf, ln1_g + l * 128, ln1_b + l * 128);

    // f = relu(t @ W1^T + b1) bf16 ; pre = t + f @ W2^T + b2 ; ln2 -> t
    mm_kernel<4, true, true, false><<<dim3(32, 32), 64, 0, stream>>>(
        t_bf, 128, 0, ff1_w + l * 262144, 128, 0, ff1_b + l * 2048,
        nullf, nullf, fb, nullb, 2048, 0, 128, 1.f);
    mm_kernel<2, true, false, false><<<dim3(32, 4), 64, 0, stream>>>(
        fb, 2048, 0, ff2_w + l * 262144, 2048, 0, ff2_b + l * 128,
        tS, pre, nullb, nullb, 128, 0, 2048, 1.f);
    ln_kernel<<<256, 256, 0, stream>>>(pre, tS, t_bf, ln2_g + l * 128, ln2_b + l * 128);
  }

  // ---- node head ----
  mm_kernel<2, true, true, false><<<dim3(32, 4), 64, 0, stream>>>(
      t_bf, 128, 0, nh1_w, 128, 0, nh1_b, nullf,
      nhmid, nullb, nullb, 128, 0, 128, 1.f);
  nh2_kernel<<<4, 256, 0, stream>>>(nhmid, nh2_w, nh2_b, out_node);

  // ---- edge MLP ----
  mm_kernel<2, true, false, false><<<dim3(32, 4), 64, 0, stream>>>(
      t_bf, 128, 0, e1_w, 256, 0, nullf, nullf,
      hib, nullb, nullb, 128, 0, 128, 1.f);
  mm_kernel<2, true, false, false><<<dim3(32, 4), 64, 0, stream>>>(
      t_bf, 128, 0, e1_w + 128, 256, 0, e1_b, nullf,
      hjbb, nullb, nullb, 128, 0, 128, 1.f);
  edge_kernel<<<dim3(16, 32), 256, 0, stream>>>(hib, hjbb, e2_w, e2_b, out_edge);

  // ---- projector (on z) ----
  mm_kernel<2, true, true, false><<<dim3(32, 4), 64, 0, stream>>>(
      z_bf, 128, 0, p1_w, 128, 0, p1_b, nullf,
      nullf, pmid, nullb, 128, 0, 128, 1.f);
  mm_kernel<2, true, false, false><<<dim3(32, 4), 64, 0, stream>>>(
      pmid, 128, 0, p2_w, 128, 0, p2_b, nullf,
      out_proj, nullb, nullb, 128, 0, 128, 1.f);
}

// Round 6
// 447.613 us; speedup vs baseline: 2.4587x; 1.0999x over previous
//
#include <hip/hip_runtime.h>
#include <math.h>

// ---------------------------------------------------------------------------
// TypeGraphModel: conv encoder (bf16 MFMA) + fused bf16-MFMA transformer.
// N=1024, D=1024, CC=64, TP=16, EMB=128, NH=4, HD=32, L=2, FF=2048
// ---------------------------------------------------------------------------

typedef float f32x4 __attribute__((ext_vector_type(4)));
typedef short bf16x8 __attribute__((ext_vector_type(8)));
typedef unsigned short u16;
typedef unsigned short us4 __attribute__((ext_vector_type(4)));
typedef unsigned int u32;

// Abramowitz-Stegun 7.1.26 erf (max abs err 1.5e-7) -> exact-GELU
__device__ __forceinline__ float gelu_fast(float v) {
  float ax = fabsf(v) * 0.70710678118654752440f;
  float t = __builtin_amdgcn_rcpf(fmaf(0.3275911f, ax, 1.f));
  float p = fmaf(1.061405429f, t, -1.453152027f);
  p = fmaf(p, t, 1.421413741f);
  p = fmaf(p, t, -0.284496736f);
  p = fmaf(p, t, 0.254829592f);
  p = p * t;
  float e = __expf(-ax * ax);
  float erfa = fmaf(-p, e, 1.f);
  float erfv = copysignf(erfa, v);
  return 0.5f * v * (1.f + erfv);
}

__device__ __forceinline__ u16 to_bf16(float v) {
  u32 u = __float_as_uint(v);
  return (u16)((u + 0x7FFFu + ((u >> 16) & 1u)) >> 16);
}
__device__ __forceinline__ u32 packbf(float a, float b) {
  return (u32)to_bf16(a) | ((u32)to_bf16(b) << 16);
}

// ---------------- fused conv1+bn+gelu -> conv2(MFMA)+bn+gelu+pool -----------
__global__ __launch_bounds__(256) void encoder_kernel(
    const float* __restrict__ x,
    const float* __restrict__ w1, const float* __restrict__ b1,
    const float* __restrict__ g1, const float* __restrict__ be1,
    const float* __restrict__ m1, const float* __restrict__ v1,
    const float* __restrict__ w2, const float* __restrict__ b2,
    const float* __restrict__ g2, const float* __restrict__ be2,
    const float* __restrict__ m2, const float* __restrict__ v2,
    u16* __restrict__ pooled_bf)
{
  const int blk = blockIdx.x;
  const int n = blk >> 1, hb = blk & 1;
  const int P0 = hb * 512;
  const int tid = threadIdx.x;

  __shared__ __align__(16) float xs[524];
  __shared__ __align__(16) u16 h1s[516 * 40];

  for (int s = tid; s < 522; s += 256) {
    int gp = P0 - 5 + s;
    xs[s] = (gp >= 0 && gp < 1024) ? x[n * 1024 + gp] : 0.f;
  }

  const int l = tid & 63;
  const int w = tid >> 6;
  const int col = l & 15;
  const int kh = l >> 4;
  const int oc = w * 16 + col;
  bf16x8 bf[5];
#pragma unroll
  for (int t = 0; t < 5; t++) {
#pragma unroll
    for (int e = 0; e < 8; e++)
      bf[t][e] = (short)to_bf16(w2[(oc * 32 + kh * 8 + e) * 5 + t]);
  }
  const float sc2 = g2[oc] * rsqrtf(v2[oc] + 1e-5f);
  const float sh2 = (b2[oc] - m2[oc]) * sc2 + be2[oc];

  const int ch = tid & 31;
  float wk[7];
#pragma unroll
  for (int k = 0; k < 7; k++) wk[k] = w1[ch * 7 + k];
  const float s1 = g1[ch] * rsqrtf(v1[ch] + 1e-5f);
  const float t1 = (b1[ch] - m1[ch]) * s1 + be1[ch];

  __syncthreads();

  const int rb = tid >> 5;
  for (int r = rb; r < 516; r += 8) {
    float acc = 0.f;
#pragma unroll
    for (int k = 0; k < 7; k++) acc += wk[k] * xs[r + k];
    int pos = P0 - 2 + r;
    u16 hv = to_bf16(gelu_fast(fmaf(acc, s1, t1)));
    h1s[r * 40 + ch] = (pos >= 0 && pos < 1024) ? hv : (u16)0;
  }
  __syncthreads();

  float pool = 0.f;
#pragma unroll 4
  for (int pt = 0; pt < 32; pt++) {
    f32x4 acc = {0.f, 0.f, 0.f, 0.f};
    const u16* ap = &h1s[(pt * 16 + col) * 40 + kh * 8];
#pragma unroll
    for (int t = 0; t < 5; t++) {
      bf16x8 af = *(const bf16x8*)(ap + t * 40);
      acc = __builtin_amdgcn_mfma_f32_16x16x32_bf16(af, bf[t], acc, 0, 0, 0);
    }
    float s = 0.f;
#pragma unroll
    for (int rr = 0; rr < 4; rr++) s += gelu_fast(fmaf(acc[rr], sc2, sh2));
    pool += s;
    if ((pt & 3) == 3) {
      pool += __shfl_xor(pool, 16);
      pool += __shfl_xor(pool, 32);
      if (l < 16)
        pooled_bf[(n * 64 + oc) * 16 + hb * 8 + (pt >> 2)] =
            to_bf16(pool * (1.f / 64.f));
      pool = 0.f;
    }
  }
}

// ---------------- weight f32 -> bf16 arena (+e1 rearrange, +bias build) -----
// Segment offsets (f32 elems): proj 0, attn_in 131072, attn_out 229376,
// ff1 262144, ff2 786432, nh1 1310720, e1 1327104, p1 1359872, p2 1376256,
// total 1392640. Block 1360 builds wbias[256] = [0]*128 + e1_b.
__global__ __launch_bounds__(256) void wconv_kernel(
    const float* __restrict__ proj_w, const float* __restrict__ attn_in_w,
    const float* __restrict__ attn_out_w, const float* __restrict__ ff1_w,
    const float* __restrict__ ff2_w, const float* __restrict__ nh1_w,
    const float* __restrict__ e1_w, const float* __restrict__ e1_b,
    const float* __restrict__ p1_w, const float* __restrict__ p2_w,
    u16* __restrict__ wbf, float* __restrict__ wbias)
{
  if (blockIdx.x == 1360) {
    int j = threadIdx.x;
    wbias[j] = (j < 128) ? 0.f : e1_b[j - 128];
    return;
  }
  int i0 = (blockIdx.x * 256 + threadIdx.x) * 4;
  float v[4];
  if (i0 < 131072) {
    const float* s = proj_w + i0;
#pragma unroll
    for (int u = 0; u < 4; u++) v[u] = s[u];
  } else if (i0 < 229376) {
    const float* s = attn_in_w + (i0 - 131072);
#pragma unroll
    for (int u = 0; u < 4; u++) v[u] = s[u];
  } else if (i0 < 262144) {
    const float* s = attn_out_w + (i0 - 229376);
#pragma unroll
    for (int u = 0; u < 4; u++) v[u] = s[u];
  } else if (i0 < 786432) {
    const float* s = ff1_w + (i0 - 262144);
#pragma unroll
    for (int u = 0; u < 4; u++) v[u] = s[u];
  } else if (i0 < 1310720) {
    const float* s = ff2_w + (i0 - 786432);
#pragma unroll
    for (int u = 0; u < 4; u++) v[u] = s[u];
  } else if (i0 < 1327104) {
    const float* s = nh1_w + (i0 - 1310720);
#pragma unroll
    for (int u = 0; u < 4; u++) v[u] = s[u];
  } else if (i0 < 1359872) {
    int j = i0 - 1327104;
#pragma unroll
    for (int u = 0; u < 4; u++) {
      int idx = j + u, nn = idx >> 7, k = idx & 127;
      v[u] = e1_w[(nn & 127) * 256 + (nn >> 7) * 128 + k];
    }
  } else if (i0 < 1376256) {
    const float* s = p1_w + (i0 - 1359872);
#pragma unroll
    for (int u = 0; u < 4; u++) v[u] = s[u];
  } else {
    const float* s = p2_w + (i0 - 1376256);
#pragma unroll
    for (int u = 0; u < 4; u++) v[u] = s[u];
  }
  us4 o;
#pragma unroll
  for (int u = 0; u < 4; u++) o[u] = to_bf16(v[u]);
  *(us4*)(wbf + i0) = o;
}

// ---------------- bf16 MFMA GEMM-NT (bf16 A and B) -------------------------
// D[m,n] = sum_k A[m,k]*B[n,k] (+bias[n]) (relu). 1 wave; 32 x NR*16 tile.
template<int NR, bool RELU, bool VT>
__global__ __launch_bounds__(64) void mm_kernel(
    const u16* __restrict__ A, int lda,
    const u16* __restrict__ B, int ldb,
    const float* __restrict__ bias,
    float* __restrict__ Cf, u16* __restrict__ Cb, u16* __restrict__ vt,
    int ldc, int K)
{
  const int m0 = blockIdx.x * 32, n0 = blockIdx.y * (NR * 16);
  const int l = threadIdx.x;
  const int r = l & 15, kh = l >> 4;

  f32x4 acc[2][NR];
#pragma unroll
  for (int i = 0; i < 2; i++)
#pragma unroll
    for (int j = 0; j < NR; j++) acc[i][j] = (f32x4){0.f, 0.f, 0.f, 0.f};

  const u16* Ap0 = A + (size_t)(m0 + r) * lda + kh * 8;
  const u16* Ap1 = Ap0 + (size_t)16 * lda;
  const u16* Bp = B + (size_t)(n0 + r) * ldb + kh * 8;

  for (int k0 = 0; k0 < K; k0 += 32) {
    bf16x8 a0 = *(const bf16x8*)(Ap0 + k0);
    bf16x8 a1 = *(const bf16x8*)(Ap1 + k0);
    bf16x8 bfr[NR];
#pragma unroll
    for (int ni = 0; ni < NR; ni++)
      bfr[ni] = *(const bf16x8*)(Bp + (size_t)ni * 16 * ldb + k0);
#pragma unroll
    for (int ni = 0; ni < NR; ni++) {
      acc[0][ni] = __builtin_amdgcn_mfma_f32_16x16x32_bf16(a0, bfr[ni], acc[0][ni], 0, 0, 0);
      acc[1][ni] = __builtin_amdgcn_mfma_f32_16x16x32_bf16(a1, bfr[ni], acc[1][ni], 0, 0, 0);
    }
  }

#pragma unroll
  for (int mi = 0; mi < 2; mi++) {
#pragma unroll
    for (int ni = 0; ni < NR; ni++) {
#pragma unroll
      for (int reg = 0; reg < 4; reg++) {
        int row = m0 + mi * 16 + kh * 4 + reg;
        int colx = n0 + ni * 16 + r;
        float v = acc[mi][ni][reg];
        if (bias) v += bias[colx];
        if (RELU) v = fmaxf(v, 0.f);
        if (Cf) Cf[(size_t)row * ldc + colx] = v;
        if (Cb) Cb[(size_t)row * ldc + colx] = to_bf16(v);
        if (VT) {
          if (colx >= 256) {
            int hv = (colx - 256) >> 5, dv = (colx - 256) & 31;
            vt[(size_t)hv * 32768 + (size_t)dv * 1024 + row] = to_bf16(v);
          }
        }
      }
    }
  }
}

// ---------------- flash attention: 1 wave = 16 q-rows x 1 head -------------
// S^T tiles via mfma(K_perm, Q); in-lane P assembly (kv=8g+4s+reg); PV via
// mfma(V^T, P). Online softmax per q (lane-local after 2 shfl).
__global__ __launch_bounds__(64) void attn_kernel(
    const u16* __restrict__ qkv, const u16* __restrict__ vt,
    u16* __restrict__ attnO)
{
  const int h = blockIdx.y, q0 = blockIdx.x * 16;
  const int l = threadIdx.x, q = l & 15, g = l >> 4;
  const float iso = 0.17677669529663689f;

  bf16x8 qf = *(const bf16x8*)(qkv + (size_t)(q0 + q) * 384 + h * 32 + g * 8);
  // permuted K row offsets: frag row r=l&15 -> kv = 8*(r>>2) + 4*s + (r&3)
  const int kvo0 = 8 * (q >> 2) + (q & 3);
  const int kvo1 = kvo0 + 4;
  const u16* kbase = qkv + 128 + h * 32 + g * 8;
  const u16* vbase = vt + (size_t)h * 32768 + (size_t)q * 1024 + g * 8;

  f32x4 o0 = {0.f, 0.f, 0.f, 0.f}, o1 = {0.f, 0.f, 0.f, 0.f};
  float m = -1e30f, lsum = 0.f;
  const f32x4 zero = {0.f, 0.f, 0.f, 0.f};

  for (int kv0 = 0; kv0 < 1024; kv0 += 32) {
    bf16x8 k0f = *(const bf16x8*)(kbase + (size_t)(kv0 + kvo0) * 384);
    bf16x8 k1f = *(const bf16x8*)(kbase + (size_t)(kv0 + kvo1) * 384);
    f32x4 s0 = __builtin_amdgcn_mfma_f32_16x16x32_bf16(k0f, qf, zero, 0, 0, 0);
    f32x4 s1 = __builtin_amdgcn_mfma_f32_16x16x32_bf16(k1f, qf, zero, 0, 0, 0);

    float tm = fmaxf(fmaxf(fmaxf(s0[0], s0[1]), fmaxf(s0[2], s0[3])),
                     fmaxf(fmaxf(s1[0], s1[1]), fmaxf(s1[2], s1[3])));
    tm = fmaxf(tm, __shfl_xor(tm, 16));
    tm = fmaxf(tm, __shfl_xor(tm, 32));
    float mn = fmaxf(m, tm);
    float corr = __expf((m - mn) * iso);

    float e0[4], e1v[4], sum = 0.f;
#pragma unroll
    for (int j = 0; j < 4; j++) {
      e0[j] = __expf((s0[j] - mn) * iso);
      e1v[j] = __expf((s1[j] - mn) * iso);
      sum += e0[j] + e1v[j];
    }
    lsum = lsum * corr + sum;
#pragma unroll
    for (int j = 0; j < 4; j++) { o0[j] *= corr; o1[j] *= corr; }

    union { u32 u[4]; bf16x8 v; } P;
    P.u[0] = packbf(e0[0], e0[1]);
    P.u[1] = packbf(e0[2], e0[3]);
    P.u[2] = packbf(e1v[0], e1v[1]);
    P.u[3] = packbf(e1v[2], e1v[3]);

    bf16x8 v0 = *(const bf16x8*)(vbase + kv0);
    bf16x8 v1 = *(const bf16x8*)(vbase + 16 * 1024 + kv0);
    o0 = __builtin_amdgcn_mfma_f32_16x16x32_bf16(v0, P.v, o0, 0, 0, 0);
    o1 = __builtin_amdgcn_mfma_f32_16x16x32_bf16(v1, P.v, o1, 0, 0, 0);
    m = mn;
  }
  lsum += __shfl_xor(lsum, 16);
  lsum += __shfl_xor(lsum, 32);
  float inv = __builtin_amdgcn_rcpf(lsum);

  us4 w0, w1;
#pragma unroll
  for (int reg = 0; reg < 4; reg++) {
    w0[reg] = to_bf16(o0[reg] * inv);
    w1[reg] = to_bf16(o1[reg] * inv);
  }
  u16* outp = attnO + (size_t)(q0 + q) * 128 + h * 32 + 4 * g;
  *(us4*)outp = w0;
  *(us4*)(outp + 16) = w1;
}

// ---------------- fused GEMM (K tmpl) + bias + residual + LayerNorm --------
// Block: 32 rows x 128 cols, 4 waves (wave w = cols 32w..32w+32).
template<int K>
__global__ __launch_bounds__(256) void owl_kernel(
    const u16* __restrict__ A, const u16* __restrict__ Bw,
    const float* __restrict__ bias, const float* __restrict__ Res,
    float* __restrict__ outF, u16* __restrict__ outB,
    const float* __restrict__ g_, const float* __restrict__ b_)
{
  __shared__ float ld[32][132];
  const int m0 = blockIdx.x * 32;
  const int tid = threadIdx.x;
  const int w = tid >> 6, l = tid & 63;
  const int r = l & 15, kg = l >> 4;

  f32x4 acc[2][2];
#pragma unroll
  for (int i = 0; i < 2; i++)
#pragma unroll
    for (int j = 0; j < 2; j++) acc[i][j] = (f32x4){0.f, 0.f, 0.f, 0.f};

  const u16* Ap0 = A + (size_t)(m0 + r) * K + kg * 8;
  const u16* Ap1 = Ap0 + (size_t)16 * K;
  const u16* Bp0 = Bw + (size_t)(w * 32 + r) * K + kg * 8;
  const u16* Bp1 = Bp0 + (size_t)16 * K;

#pragma unroll 4
  for (int k0 = 0; k0 < K; k0 += 32) {
    bf16x8 a0 = *(const bf16x8*)(Ap0 + k0);
    bf16x8 a1 = *(const bf16x8*)(Ap1 + k0);
    bf16x8 b0 = *(const bf16x8*)(Bp0 + k0);
    bf16x8 b1 = *(const bf16x8*)(Bp1 + k0);
    acc[0][0] = __builtin_amdgcn_mfma_f32_16x16x32_bf16(a0, b0, acc[0][0], 0, 0, 0);
    acc[0][1] = __builtin_amdgcn_mfma_f32_16x16x32_bf16(a0, b1, acc[0][1], 0, 0, 0);
    acc[1][0] = __builtin_amdgcn_mfma_f32_16x16x32_bf16(a1, b0, acc[1][0], 0, 0, 0);
    acc[1][1] = __builtin_amdgcn_mfma_f32_16x16x32_bf16(a1, b1, acc[1][1], 0, 0, 0);
  }

#pragma unroll
  for (int mi = 0; mi < 2; mi++)
#pragma unroll
    for (int ni = 0; ni < 2; ni++)
#pragma unroll
      for (int reg = 0; reg < 4; reg++) {
        int row = mi * 16 + kg * 4 + reg;
        int col = w * 32 + ni * 16 + r;
        ld[row][col] = acc[mi][ni][reg] + bias[col] +
                       Res[(size_t)(m0 + row) * 128 + col];
      }
  __syncthreads();

  // LN: 8 threads per row (tid>>3 = row, tid&7 = 16-col slice)
  const int row = tid >> 3, s8 = tid & 7;
  f32x4 vv[4];
  float sum = 0.f, ss = 0.f;
#pragma unroll
  for (int u = 0; u < 4; u++) {
    vv[u] = *(const f32x4*)&ld[row][s8 * 16 + u * 4];
#pragma unroll
    for (int j = 0; j < 4; j++) { sum += vv[u][j]; ss += vv[u][j] * vv[u][j]; }
  }
#pragma unroll
  for (int off = 1; off <= 4; off <<= 1) {
    sum += __shfl_xor(sum, off);
    ss += __shfl_xor(ss, off);
  }
  float mu = sum * (1.f / 128.f);
  float var = ss * (1.f / 128.f) - mu * mu;
  float inv = rsqrtf(var + 1e-5f);
  size_t base = (size_t)(m0 + row) * 128;
#pragma unroll
  for (int u = 0; u < 4; u++) {
    int c = s8 * 16 + u * 4;
    f32x4 gv = *(const f32x4*)(g_ + c);
    f32x4 bv = *(const f32x4*)(b_ + c);
    f32x4 o;
    us4 ob;
#pragma unroll
    for (int j = 0; j < 4; j++) {
      o[j] = (vv[u][j] - mu) * inv * gv[j] + bv[j];
      ob[j] = to_bf16(o[j]);
    }
    *(f32x4*)(outF + base + c) = o;
    *(us4*)(outB + base + c) = ob;
  }
}

// ---------------- node head second layer (N=3) -----------------------------
__global__ __launch_bounds__(256) void nh2_kernel(
    const float* __restrict__ mid, const float* __restrict__ w,
    const float* __restrict__ b, float* __restrict__ out)
{
  int m = blockIdx.x * 256 + threadIdx.x;
  const float* row = mid + (size_t)m * 128;
  float a0 = 0.f, a1 = 0.f, a2 = 0.f;
#pragma unroll 4
  for (int k = 0; k < 128; k++) {
    float xv = row[k];
    a0 += xv * w[k]; a1 += xv * w[128 + k]; a2 += xv * w[256 + k];
  }
  out[m * 3 + 0] = a0 + b[0];
  out[m * 3 + 1] = a1 + b[1];
  out[m * 3 + 2] = a2 + b[2];
}

// ---------------- all-pairs edge over combined [hi|hj+b] buffer ------------
// comb[tok][0:128]=hi, comb[tok][128:256]=hj+e1_b.
__global__ __launch_bounds__(256) void edge_kernel(
    const float* __restrict__ comb,
    const float* __restrict__ w, const float* __restrict__ e2b,
    float* __restrict__ out)
{
  const int i0 = blockIdx.x * 64;
  const int j0 = blockIdx.y * 32;
  __shared__ float his[128][64];
  __shared__ float hjs[128][32];
  const int tid = threadIdx.x;
  {
    int r = tid >> 2, c0 = (tid & 3) * 32;
#pragma unroll
    for (int u = 0; u < 8; u++) {
      float4 v = *(const float4*)(comb + (size_t)(i0 + r) * 256 + c0 + u * 4);
      his[c0 + u * 4 + 0][r] = v.x; his[c0 + u * 4 + 1][r] = v.y;
      his[c0 + u * 4 + 2][r] = v.z; his[c0 + u * 4 + 3][r] = v.w;
    }
  }
  {
    int r = tid >> 3, c0 = (tid & 7) * 16;
#pragma unroll
    for (int u = 0; u < 4; u++) {
      float4 v = *(const float4*)(comb + (size_t)(j0 + r) * 256 + 128 + c0 + u * 4);
      hjs[c0 + u * 4 + 0][r] = v.x; hjs[c0 + u * 4 + 1][r] = v.y;
      hjs[c0 + u * 4 + 2][r] = v.z; hjs[c0 + u * 4 + 3][r] = v.w;
    }
  }
  __syncthreads();
  const int il = (tid & 15) * 4, jl = (tid >> 4) * 2;
  float acc[4][2] = {{0.f,0.f},{0.f,0.f},{0.f,0.f},{0.f,0.f}};
  for (int e = 0; e < 128; e++) {
    float4 a = *(const float4*)&his[e][il];
    float2 bv = *(const float2*)&hjs[e][jl];
    float we = w[e];
    float av[4] = {a.x, a.y, a.z, a.w};
    float bb[2] = {bv.x, bv.y};
#pragma unroll
    for (int ii = 0; ii < 4; ii++)
#pragma unroll
      for (int jj = 0; jj < 2; jj++)
        acc[ii][jj] += fmaxf(av[ii] + bb[jj], 0.f) * we;
  }
  float eb = e2b[0];
#pragma unroll
  for (int ii = 0; ii < 4; ii++) {
    float2 vv = make_float2(acc[ii][0] + eb, acc[ii][1] + eb);
    *(float2*)(out + (size_t)(i0 + il + ii) * 1024 + j0 + jl) = vv;
  }
}

// ---------------------------------------------------------------------------
extern "C" void kernel_launch(void* const* d_in, const int* in_sizes, int n_in,
                              void* d_out, int out_size, void* d_ws, size_t ws_size,
                              hipStream_t stream)
{
  const float* x        = (const float*)d_in[0];
  const float* conv1_w  = (const float*)d_in[1];
  const float* conv1_b  = (const float*)d_in[2];
  const float* bn1_g    = (const float*)d_in[3];
  const float* bn1_b    = (const float*)d_in[4];
  const float* bn1_m    = (const float*)d_in[5];
  const float* bn1_v    = (const float*)d_in[6];
  const float* conv2_w  = (const float*)d_in[7];
  const float* conv2_b  = (const float*)d_in[8];
  const float* bn2_g    = (const float*)d_in[9];
  const float* bn2_b    = (const float*)d_in[10];
  const float* bn2_m    = (const float*)d_in[11];
  const float* bn2_v    = (const float*)d_in[12];
  const float* proj_w   = (const float*)d_in[13];
  const float* proj_b   = (const float*)d_in[14];
  const float* attn_in_w  = (const float*)d_in[15];
  const float* attn_in_b  = (const float*)d_in[16];
  const float* attn_out_w = (const float*)d_in[17];
  const float* attn_out_b = (const float*)d_in[18];
  const float* ln1_g    = (const float*)d_in[19];
  const float* ln1_b    = (const float*)d_in[20];
  const float* ff1_w    = (const float*)d_in[21];
  const float* ff1_b    = (const float*)d_in[22];
  const float* ff2_w    = (const float*)d_in[23];
  const float* ff2_b    = (const float*)d_in[24];
  const float* ln2_g    = (const float*)d_in[25];
  const float* ln2_b    = (const float*)d_in[26];
  const float* nh1_w    = (const float*)d_in[27];
  const float* nh1_b    = (const float*)d_in[28];
  const float* nh2_w    = (const float*)d_in[29];
  const float* nh2_b    = (const float*)d_in[30];
  const float* e1_w     = (const float*)d_in[31];
  const float* e1_b     = (const float*)d_in[32];
  const float* e2_w     = (const float*)d_in[33];
  const float* e2_b     = (const float*)d_in[34];
  const float* p1_w     = (const float*)d_in[35];
  const float* p1_b     = (const float*)d_in[36];
  const float* p2_w     = (const float*)d_in[37];
  const float* p2_b     = (const float*)d_in[38];

  float* ws = (float*)d_ws;

  // Fixed arena (f32 units), total 2,334,976 f32 = 8.91 MiB.
  u16*  wbf    = (u16*)ws;                       // 1392640 u16
  float* wbias = ws + 696320;                    // 256 f32
  float* z     = ws + 696576;                    // 131072
  u16*  z_bf   = (u16*)(ws + 827648);            // 131072 u16
  float* tS    = ws + 893184;                    // 131072
  u16*  t_bf   = (u16*)(ws + 1024256);           // 131072 u16
  u16*  qkv_bf = (u16*)(ws + 1089792);           // 393216 u16
  float* R     = ws + 1286400;                   // 1048576 f32 shared region
  // R aliases (time-shared): pooled_bf / (attnO|vt) / fb / head buffers
  u16*  pooled_bf = (u16*)R;                     // 1024x1024 u16
  u16*  attnO  = (u16*)R;                        // 1024x128 u16
  u16*  vt     = (u16*)R + 131072;               // [4][32][1024] u16
  u16*  fb     = (u16*)R;                        // 1024x2048 u16
  float* nhmid = R;                              // 1024x128 f32
  float* e1out = R + 131072;                     // 1024x256 f32
  u16*  pmid   = (u16*)(R + 393216);             // 1024x128 u16

  float* out_node = (float*)d_out;
  float* out_edge = out_node + 3072;
  float* out_proj = out_edge + 1048576;

  float* nullf = nullptr; u16* nullb = nullptr;

  // weights -> bf16 arena (+ e1 rearrange + bias build)
  wconv_kernel<<<1361, 256, 0, stream>>>(
      proj_w, attn_in_w, attn_out_w, ff1_w, ff2_w, nh1_w, e1_w, e1_b,
      p1_w, p2_w, wbf, wbias);

  // encoder -> pooled bf16
  encoder_kernel<<<2048, 256, 0, stream>>>(
      x, conv1_w, conv1_b, bn1_g, bn1_b, bn1_m, bn1_v,
      conv2_w, conv2_b, bn2_g, bn2_b, bn2_m, bn2_v, pooled_bf);

  // z = pooled @ proj_w^T + proj_b
  mm_kernel<2, false, false><<<dim3(32, 4), 64, 0, stream>>>(
      pooled_bf, 1024, wbf, 1024, proj_b, z, z_bf, nullb, 128, 1024);

  for (int l = 0; l < 2; l++) {
    const float* resIn = l ? tS : z;
    const u16* tin_bf = l ? t_bf : z_bf;
    // qkv (+ V-transpose scatter into vt)
    mm_kernel<4, false, true><<<dim3(32, 6), 64, 0, stream>>>(
        tin_bf, 128, wbf + 131072 + l * 49152, 128, attn_in_b + l * 384,
        nullf, qkv_bf, vt, 384, 128);
    // fused flash attention -> attnO bf16
    attn_kernel<<<dim3(64, 4), 64, 0, stream>>>(qkv_bf, vt, attnO);
    // t = LN1(resIn + attnO @ Wo^T + bo)
    owl_kernel<128><<<32, 256, 0, stream>>>(
        attnO, wbf + 229376 + l * 16384, attn_out_b + l * 128, resIn,
        tS, t_bf, ln1_g + l * 128, ln1_b + l * 128);
    // f = relu(t @ W1^T + b1)
    mm_kernel<4, true, false><<<dim3(32, 32), 64, 0, stream>>>(
        t_bf, 128, wbf + 262144 + l * 262144, 128, ff1_b + l * 2048,
        nullf, fb, nullb, 2048, 128);
    // t = LN2(t + f @ W2^T + b2)
    owl_kernel<2048><<<32, 256, 0, stream>>>(
        fb, wbf + 786432 + l * 262144, ff2_b + l * 128, tS,
        tS, t_bf, ln2_g + l * 128, ln2_b + l * 128);
  }

  // node head
  mm_kernel<2, true, false><<<dim3(32, 4), 64, 0, stream>>>(
      t_bf, 128, wbf + 1310720, 128, nh1_b, nhmid, nullb, nullb, 128, 128);
  nh2_kernel<<<4, 256, 0, stream>>>(nhmid, nh2_w, nh2_b, out_node);

  // edge MLP: combined [hi | hj + e1_b] then all-pairs
  mm_kernel<2, false, false><<<dim3(32, 8), 64, 0, stream>>>(
      t_bf, 128, wbf + 1327104, 128, wbias, e1out, nullb, nullb, 256, 128);
  edge_kernel<<<dim3(16, 32), 256, 0, stream>>>(e1out, e2_w, e2_b, out_edge);

  // projector (on z)
  mm_kernel<2, true, false><<<dim3(32, 4), 64, 0, stream>>>(
      z_bf, 128, wbf + 1359872, 128, p1_b, nullf, pmid, nullb, 128, 128);
  mm_kernel<2, false, false><<<dim3(32, 4), 64, 0, stream>>>(
      pmid, 128, wbf + 1376256, 128, p2_b, out_proj, nullb, nullb, 128, 128);
}

// Round 8
// 422.423 us; speedup vs baseline: 2.6053x; 1.0596x over previous
//
#include <hip/hip_runtime.h>
#include <math.h>

// ---------------------------------------------------------------------------
// TypeGraphModel: conv encoder (bf16 MFMA) + fused bf16-MFMA transformer.
// N=1024, D=1024, CC=64, TP=16, EMB=128, NH=4, HD=32, L=2, FF=2048
// ---------------------------------------------------------------------------

typedef float f32x4 __attribute__((ext_vector_type(4)));
typedef short bf16x8 __attribute__((ext_vector_type(8)));
typedef unsigned short u16;
typedef unsigned short us4 __attribute__((ext_vector_type(4)));
typedef unsigned int u32;

// Abramowitz-Stegun 7.1.26 erf (max abs err 1.5e-7) -> exact-GELU
__device__ __forceinline__ float gelu_fast(float v) {
  float ax = fabsf(v) * 0.70710678118654752440f;
  float t = __builtin_amdgcn_rcpf(fmaf(0.3275911f, ax, 1.f));
  float p = fmaf(1.061405429f, t, -1.453152027f);
  p = fmaf(p, t, 1.421413741f);
  p = fmaf(p, t, -0.284496736f);
  p = fmaf(p, t, 0.254829592f);
  p = p * t;
  float e = __expf(-ax * ax);
  float erfa = fmaf(-p, e, 1.f);
  float erfv = copysignf(erfa, v);
  return 0.5f * v * (1.f + erfv);
}

__device__ __forceinline__ u16 to_bf16(float v) {
  u32 u = __float_as_uint(v);
  return (u16)((u + 0x7FFFu + ((u >> 16) & 1u)) >> 16);
}
__device__ __forceinline__ u32 packbf(float a, float b) {
  return (u32)to_bf16(a) | ((u32)to_bf16(b) << 16);
}

// ---------------- fused conv1+bn+gelu -> conv2(MFMA)+bn+gelu+pool -----------
__global__ __launch_bounds__(256) void encoder_kernel(
    const float* __restrict__ x,
    const float* __restrict__ w1, const float* __restrict__ b1,
    const float* __restrict__ g1, const float* __restrict__ be1,
    const float* __restrict__ m1, const float* __restrict__ v1,
    const float* __restrict__ w2, const float* __restrict__ b2,
    const float* __restrict__ g2, const float* __restrict__ be2,
    const float* __restrict__ m2, const float* __restrict__ v2,
    u16* __restrict__ pooled_bf)
{
  const int blk = blockIdx.x;
  const int n = blk >> 1, hb = blk & 1;
  const int P0 = hb * 512;
  const int tid = threadIdx.x;

  __shared__ __align__(16) float xs[524];
  __shared__ __align__(16) u16 h1s[516 * 40];

  for (int s = tid; s < 522; s += 256) {
    int gp = P0 - 5 + s;
    xs[s] = (gp >= 0 && gp < 1024) ? x[n * 1024 + gp] : 0.f;
  }

  const int l = tid & 63;
  const int w = tid >> 6;
  const int col = l & 15;
  const int kh = l >> 4;
  const int oc = w * 16 + col;
  bf16x8 bf[5];
#pragma unroll
  for (int t = 0; t < 5; t++) {
#pragma unroll
    for (int e = 0; e < 8; e++)
      bf[t][e] = (short)to_bf16(w2[(oc * 32 + kh * 8 + e) * 5 + t]);
  }
  const float sc2 = g2[oc] * rsqrtf(v2[oc] + 1e-5f);
  const float sh2 = (b2[oc] - m2[oc]) * sc2 + be2[oc];

  const int ch = tid & 31;
  float wk[7];
#pragma unroll
  for (int k = 0; k < 7; k++) wk[k] = w1[ch * 7 + k];
  const float s1 = g1[ch] * rsqrtf(v1[ch] + 1e-5f);
  const float t1 = (b1[ch] - m1[ch]) * s1 + be1[ch];

  __syncthreads();

  const int rb = tid >> 5;
  for (int r = rb; r < 516; r += 8) {
    float acc = 0.f;
#pragma unroll
    for (int k = 0; k < 7; k++) acc += wk[k] * xs[r + k];
    int pos = P0 - 2 + r;
    u16 hv = to_bf16(gelu_fast(fmaf(acc, s1, t1)));
    h1s[r * 40 + ch] = (pos >= 0 && pos < 1024) ? hv : (u16)0;
  }
  __syncthreads();

  float pool = 0.f;
#pragma unroll 4
  for (int pt = 0; pt < 32; pt++) {
    f32x4 acc = {0.f, 0.f, 0.f, 0.f};
    const u16* ap = &h1s[(pt * 16 + col) * 40 + kh * 8];
#pragma unroll
    for (int t = 0; t < 5; t++) {
      bf16x8 af = *(const bf16x8*)(ap + t * 40);
      acc = __builtin_amdgcn_mfma_f32_16x16x32_bf16(af, bf[t], acc, 0, 0, 0);
    }
    float s = 0.f;
#pragma unroll
    for (int rr = 0; rr < 4; rr++) s += gelu_fast(fmaf(acc[rr], sc2, sh2));
    pool += s;
    if ((pt & 3) == 3) {
      pool += __shfl_xor(pool, 16);
      pool += __shfl_xor(pool, 32);
      if (l < 16)
        pooled_bf[(n * 64 + oc) * 16 + hb * 8 + (pt >> 2)] =
            to_bf16(pool * (1.f / 64.f));
      pool = 0.f;
    }
  }
}

// ---------------- weight f32 -> bf16 arena (+e1 rearrange, +bias build) -----
__global__ __launch_bounds__(256) void wconv_kernel(
    const float* __restrict__ proj_w, const float* __restrict__ attn_in_w,
    const float* __restrict__ attn_out_w, const float* __restrict__ ff1_w,
    const float* __restrict__ ff2_w, const float* __restrict__ nh1_w,
    const float* __restrict__ e1_w, const float* __restrict__ e1_b,
    const float* __restrict__ p1_w, const float* __restrict__ p2_w,
    u16* __restrict__ wbf, float* __restrict__ wbias)
{
  if (blockIdx.x == 1360) {
    int j = threadIdx.x;
    wbias[j] = (j < 128) ? 0.f : e1_b[j - 128];
    return;
  }
  int i0 = (blockIdx.x * 256 + threadIdx.x) * 4;
  float v[4];
  if (i0 < 131072) {
    const float* s = proj_w + i0;
#pragma unroll
    for (int u = 0; u < 4; u++) v[u] = s[u];
  } else if (i0 < 229376) {
    const float* s = attn_in_w + (i0 - 131072);
#pragma unroll
    for (int u = 0; u < 4; u++) v[u] = s[u];
  } else if (i0 < 262144) {
    const float* s = attn_out_w + (i0 - 229376);
#pragma unroll
    for (int u = 0; u < 4; u++) v[u] = s[u];
  } else if (i0 < 786432) {
    const float* s = ff1_w + (i0 - 262144);
#pragma unroll
    for (int u = 0; u < 4; u++) v[u] = s[u];
  } else if (i0 < 1310720) {
    const float* s = ff2_w + (i0 - 786432);
#pragma unroll
    for (int u = 0; u < 4; u++) v[u] = s[u];
  } else if (i0 < 1327104) {
    const float* s = nh1_w + (i0 - 1310720);
#pragma unroll
    for (int u = 0; u < 4; u++) v[u] = s[u];
  } else if (i0 < 1359872) {
    int j = i0 - 1327104;
#pragma unroll
    for (int u = 0; u < 4; u++) {
      int idx = j + u, nn = idx >> 7, k = idx & 127;
      v[u] = e1_w[(nn & 127) * 256 + (nn >> 7) * 128 + k];
    }
  } else if (i0 < 1376256) {
    const float* s = p1_w + (i0 - 1359872);
#pragma unroll
    for (int u = 0; u < 4; u++) v[u] = s[u];
  } else {
    const float* s = p2_w + (i0 - 1376256);
#pragma unroll
    for (int u = 0; u < 4; u++) v[u] = s[u];
  }
  us4 o;
#pragma unroll
  for (int u = 0; u < 4; u++) o[u] = to_bf16(v[u]);
  *(us4*)(wbf + i0) = o;
}

// ---------------- bf16 MFMA GEMM-NT, compile-time K ------------------------
// D[m,n] = sum_k A[m,k]*B[n,k] (+bias[n]) (relu). 1 wave; 32 x NR*16 tile.
// K template + unroll 4 -> compiler hoists each group's loads (latency hide).
template<int NR, int K, bool RELU, bool VT>
__global__ __launch_bounds__(64) void mm_kernel(
    const u16* __restrict__ A, int lda,
    const u16* __restrict__ B, int ldb,
    const float* __restrict__ bias,
    float* __restrict__ Cf, u16* __restrict__ Cb, u16* __restrict__ vt,
    int ldc)
{
  const int m0 = blockIdx.x * 32, n0 = blockIdx.y * (NR * 16);
  const int l = threadIdx.x;
  const int r = l & 15, kh = l >> 4;

  f32x4 acc[2][NR];
#pragma unroll
  for (int i = 0; i < 2; i++)
#pragma unroll
    for (int j = 0; j < NR; j++) acc[i][j] = (f32x4){0.f, 0.f, 0.f, 0.f};

  const u16* Ap0 = A + (size_t)(m0 + r) * lda + kh * 8;
  const u16* Ap1 = Ap0 + (size_t)16 * lda;
  const u16* Bp = B + (size_t)(n0 + r) * ldb + kh * 8;

#pragma unroll 4
  for (int k0 = 0; k0 < K; k0 += 32) {
    bf16x8 a0 = *(const bf16x8*)(Ap0 + k0);
    bf16x8 a1 = *(const bf16x8*)(Ap1 + k0);
    bf16x8 bfr[NR];
#pragma unroll
    for (int ni = 0; ni < NR; ni++)
      bfr[ni] = *(const bf16x8*)(Bp + (size_t)ni * 16 * ldb + k0);
#pragma unroll
    for (int ni = 0; ni < NR; ni++) {
      acc[0][ni] = __builtin_amdgcn_mfma_f32_16x16x32_bf16(a0, bfr[ni], acc[0][ni], 0, 0, 0);
      acc[1][ni] = __builtin_amdgcn_mfma_f32_16x16x32_bf16(a1, bfr[ni], acc[1][ni], 0, 0, 0);
    }
  }

#pragma unroll
  for (int mi = 0; mi < 2; mi++) {
#pragma unroll
    for (int ni = 0; ni < NR; ni++) {
#pragma unroll
      for (int reg = 0; reg < 4; reg++) {
        int row = m0 + mi * 16 + kh * 4 + reg;
        int colx = n0 + ni * 16 + r;
        float v = acc[mi][ni][reg];
        if (bias) v += bias[colx];
        if (RELU) v = fmaxf(v, 0.f);
        if (Cf) Cf[(size_t)row * ldc + colx] = v;
        if (Cb) Cb[(size_t)row * ldc + colx] = to_bf16(v);
        if (VT) {
          if (colx >= 256) {
            int hv = (colx - 256) >> 5, dv = (colx - 256) & 31;
            vt[(size_t)hv * 32768 + (size_t)dv * 1024 + row] = to_bf16(v);
          }
        }
      }
    }
  }
}

// ---------------- flash attention: 1 wave = 16 q-rows x 1 head -------------
// 2-deep register prefetch of K/V fragments hides L2 latency under softmax.
__global__ __launch_bounds__(64) void attn_kernel(
    const u16* __restrict__ qkv, const u16* __restrict__ vt,
    u16* __restrict__ attnO)
{
  const int h = blockIdx.y, q0 = blockIdx.x * 16;
  const int l = threadIdx.x, q = l & 15, g = l >> 4;
  const float iso = 0.17677669529663689f;

  bf16x8 qf = *(const bf16x8*)(qkv + (size_t)(q0 + q) * 384 + h * 32 + g * 8);
  const int kvo0 = 8 * (q >> 2) + (q & 3);
  const int kvo1 = kvo0 + 4;
  const u16* kbase = qkv + 128 + h * 32 + g * 8;
  const u16* vbase = vt + (size_t)h * 32768 + (size_t)q * 1024 + g * 8;

  f32x4 o0 = {0.f, 0.f, 0.f, 0.f}, o1 = {0.f, 0.f, 0.f, 0.f};
  float m = -1e30f, lsum = 0.f;
  const f32x4 zero = {0.f, 0.f, 0.f, 0.f};

  bf16x8 k0c = *(const bf16x8*)(kbase + (size_t)kvo0 * 384);
  bf16x8 k1c = *(const bf16x8*)(kbase + (size_t)kvo1 * 384);
  bf16x8 v0c = *(const bf16x8*)(vbase);
  bf16x8 v1c = *(const bf16x8*)(vbase + 16 * 1024);

  for (int kv0 = 0; kv0 < 1024; kv0 += 32) {
    const int nx = (kv0 + 32 < 1024) ? kv0 + 32 : kv0;
    bf16x8 k0n = *(const bf16x8*)(kbase + (size_t)(nx + kvo0) * 384);
    bf16x8 k1n = *(const bf16x8*)(kbase + (size_t)(nx + kvo1) * 384);
    bf16x8 v0n = *(const bf16x8*)(vbase + nx);
    bf16x8 v1n = *(const bf16x8*)(vbase + 16 * 1024 + nx);

    f32x4 s0 = __builtin_amdgcn_mfma_f32_16x16x32_bf16(k0c, qf, zero, 0, 0, 0);
    f32x4 s1 = __builtin_amdgcn_mfma_f32_16x16x32_bf16(k1c, qf, zero, 0, 0, 0);

    float tm = fmaxf(fmaxf(fmaxf(s0[0], s0[1]), fmaxf(s0[2], s0[3])),
                     fmaxf(fmaxf(s1[0], s1[1]), fmaxf(s1[2], s1[3])));
    tm = fmaxf(tm, __shfl_xor(tm, 16));
    tm = fmaxf(tm, __shfl_xor(tm, 32));
    float mn = fmaxf(m, tm);
    float corr = __expf((m - mn) * iso);

    float e0[4], e1v[4], sum = 0.f;
#pragma unroll
    for (int j = 0; j < 4; j++) {
      e0[j] = __expf((s0[j] - mn) * iso);
      e1v[j] = __expf((s1[j] - mn) * iso);
      sum += e0[j] + e1v[j];
    }
    lsum = lsum * corr + sum;
#pragma unroll
    for (int j = 0; j < 4; j++) { o0[j] *= corr; o1[j] *= corr; }

    union { u32 u[4]; bf16x8 v; } P;
    P.u[0] = packbf(e0[0], e0[1]);
    P.u[1] = packbf(e0[2], e0[3]);
    P.u[2] = packbf(e1v[0], e1v[1]);
    P.u[3] = packbf(e1v[2], e1v[3]);

    o0 = __builtin_amdgcn_mfma_f32_16x16x32_bf16(v0c, P.v, o0, 0, 0, 0);
    o1 = __builtin_amdgcn_mfma_f32_16x16x32_bf16(v1c, P.v, o1, 0, 0, 0);
    m = mn;
    k0c = k0n; k1c = k1n; v0c = v0n; v1c = v1n;
  }
  lsum += __shfl_xor(lsum, 16);
  lsum += __shfl_xor(lsum, 32);
  float inv = __builtin_amdgcn_rcpf(lsum);

  us4 w0, w1;
#pragma unroll
  for (int reg = 0; reg < 4; reg++) {
    w0[reg] = to_bf16(o0[reg] * inv);
    w1[reg] = to_bf16(o1[reg] * inv);
  }
  u16* outp = attnO + (size_t)(q0 + q) * 128 + h * 32 + 4 * g;
  *(us4*)outp = w0;
  *(us4*)(outp + 16) = w1;
}

// ---------------- fused GEMM K=128 + bias + residual + LayerNorm -----------
__global__ __launch_bounds__(256) void owl_kernel(
    const u16* __restrict__ A, const u16* __restrict__ Bw,
    const float* __restrict__ bias, const float* __restrict__ Res,
    float* __restrict__ outF, u16* __restrict__ outB,
    const float* __restrict__ g_, const float* __restrict__ b_)
{
  __shared__ float ld[32][132];
  const int m0 = blockIdx.x * 32;
  const int tid = threadIdx.x;
  const int w = tid >> 6, l = tid & 63;
  const int r = l & 15, kg = l >> 4;

  f32x4 acc[2][2];
#pragma unroll
  for (int i = 0; i < 2; i++)
#pragma unroll
    for (int j = 0; j < 2; j++) acc[i][j] = (f32x4){0.f, 0.f, 0.f, 0.f};

  const u16* Ap0 = A + (size_t)(m0 + r) * 128 + kg * 8;
  const u16* Ap1 = Ap0 + (size_t)16 * 128;
  const u16* Bp0 = Bw + (size_t)(w * 32 + r) * 128 + kg * 8;
  const u16* Bp1 = Bp0 + (size_t)16 * 128;

#pragma unroll
  for (int k0 = 0; k0 < 128; k0 += 32) {
    bf16x8 a0 = *(const bf16x8*)(Ap0 + k0);
    bf16x8 a1 = *(const bf16x8*)(Ap1 + k0);
    bf16x8 b0 = *(const bf16x8*)(Bp0 + k0);
    bf16x8 b1 = *(const bf16x8*)(Bp1 + k0);
    acc[0][0] = __builtin_amdgcn_mfma_f32_16x16x32_bf16(a0, b0, acc[0][0], 0, 0, 0);
    acc[0][1] = __builtin_amdgcn_mfma_f32_16x16x32_bf16(a0, b1, acc[0][1], 0, 0, 0);
    acc[1][0] = __builtin_amdgcn_mfma_f32_16x16x32_bf16(a1, b0, acc[1][0], 0, 0, 0);
    acc[1][1] = __builtin_amdgcn_mfma_f32_16x16x32_bf16(a1, b1, acc[1][1], 0, 0, 0);
  }

#pragma unroll
  for (int mi = 0; mi < 2; mi++)
#pragma unroll
    for (int ni = 0; ni < 2; ni++)
#pragma unroll
      for (int reg = 0; reg < 4; reg++) {
        int row = mi * 16 + kg * 4 + reg;
        int col = w * 32 + ni * 16 + r;
        ld[row][col] = acc[mi][ni][reg] + bias[col] +
                       Res[(size_t)(m0 + row) * 128 + col];
      }
  __syncthreads();

  const int row = tid >> 3, s8 = tid & 7;
  f32x4 vv[4];
  float sum = 0.f, ss = 0.f;
#pragma unroll
  for (int u = 0; u < 4; u++) {
    vv[u] = *(const f32x4*)&ld[row][s8 * 16 + u * 4];
#pragma unroll
    for (int j = 0; j < 4; j++) { sum += vv[u][j]; ss += vv[u][j] * vv[u][j]; }
  }
#pragma unroll
  for (int off = 1; off <= 4; off <<= 1) {
    sum += __shfl_xor(sum, off);
    ss += __shfl_xor(ss, off);
  }
  float mu = sum * (1.f / 128.f);
  float var = ss * (1.f / 128.f) - mu * mu;
  float inv = rsqrtf(var + 1e-5f);
  size_t base = (size_t)(m0 + row) * 128;
#pragma unroll
  for (int u = 0; u < 4; u++) {
    int c = s8 * 16 + u * 4;
    f32x4 gv = *(const f32x4*)(g_ + c);
    f32x4 bv = *(const f32x4*)(b_ + c);
    f32x4 o;
    us4 ob;
#pragma unroll
    for (int j = 0; j < 4; j++) {
      o[j] = (vv[u][j] - mu) * inv * gv[j] + bv[j];
      ob[j] = to_bf16(o[j]);
    }
    *(f32x4*)(outF + base + c) = o;
    *(us4*)(outB + base + c) = ob;
  }
}

// ---------------- residual + LN over pre (ff2 output) ----------------------
__global__ __launch_bounds__(256) void ln2r_kernel(
    const float* __restrict__ pre, float* __restrict__ tS, u16* __restrict__ t_bf,
    const float* __restrict__ g_, const float* __restrict__ b_)
{
  int row = blockIdx.x * 4 + (threadIdx.x >> 6);
  int lane = threadIdx.x & 63;
  size_t idx = (size_t)row * 128 + lane * 2;
  float2 pv = *(const float2*)(pre + idx);
  float2 rv = *(const float2*)(tS + idx);
  float vx = pv.x + rv.x, vy = pv.y + rv.y;
  float s = vx + vy;
#pragma unroll
  for (int off = 32; off >= 1; off >>= 1) s += __shfl_xor(s, off);
  float mu = s * (1.f / 128.f);
  float dx = vx - mu, dy = vy - mu;
  float q = dx * dx + dy * dy;
#pragma unroll
  for (int off = 32; off >= 1; off >>= 1) q += __shfl_xor(q, off);
  float inv = rsqrtf(q * (1.f / 128.f) + 1e-5f);
  float2 gv = *(const float2*)(g_ + lane * 2);
  float2 bv = *(const float2*)(b_ + lane * 2);
  float ox = dx * inv * gv.x + bv.x, oy = dy * inv * gv.y + bv.y;
  tS[idx] = ox; tS[idx + 1] = oy;
  t_bf[idx] = to_bf16(ox); t_bf[idx + 1] = to_bf16(oy);
}

// ---------------- node head second layer (N=3), 4 lanes/row ---------------
__global__ __launch_bounds__(256) void nh2_kernel(
    const float* __restrict__ mid, const float* __restrict__ w,
    const float* __restrict__ b, float* __restrict__ out)
{
  __shared__ float wsm[384];
  for (int i = threadIdx.x; i < 384; i += 256) wsm[i] = w[i];
  __syncthreads();
  int r = blockIdx.x * 64 + (threadIdx.x >> 2);
  int q = threadIdx.x & 3;
  const float* rp = mid + (size_t)r * 128 + q * 32;
  float a0 = 0.f, a1 = 0.f, a2 = 0.f;
#pragma unroll
  for (int u = 0; u < 8; u++) {
    float4 v = *(const float4*)(rp + u * 4);
    int k = q * 32 + u * 4;
    float xv[4] = {v.x, v.y, v.z, v.w};
#pragma unroll
    for (int j = 0; j < 4; j++) {
      a0 += xv[j] * wsm[k + j];
      a1 += xv[j] * wsm[128 + k + j];
      a2 += xv[j] * wsm[256 + k + j];
    }
  }
  a0 += __shfl_xor(a0, 1); a0 += __shfl_xor(a0, 2);
  a1 += __shfl_xor(a1, 1); a1 += __shfl_xor(a1, 2);
  a2 += __shfl_xor(a2, 1); a2 += __shfl_xor(a2, 2);
  if (q == 0) {
    out[r * 3 + 0] = a0 + b[0];
    out[r * 3 + 1] = a1 + b[1];
    out[r * 3 + 2] = a2 + b[2];
  }
}

// ---------------- all-pairs edge over combined [hi|hj+b] buffer ------------
__global__ __launch_bounds__(256) void edge_kernel(
    const float* __restrict__ comb,
    const float* __restrict__ w, const float* __restrict__ e2b,
    float* __restrict__ out)
{
  const int i0 = blockIdx.x * 64;
  const int j0 = blockIdx.y * 32;
  __shared__ float his[128][64];
  __shared__ float hjs[128][32];
  const int tid = threadIdx.x;
  {
    int r = tid >> 2, c0 = (tid & 3) * 32;
#pragma unroll
    for (int u = 0; u < 8; u++) {
      float4 v = *(const float4*)(comb + (size_t)(i0 + r) * 256 + c0 + u * 4);
      his[c0 + u * 4 + 0][r] = v.x; his[c0 + u * 4 + 1][r] = v.y;
      his[c0 + u * 4 + 2][r] = v.z; his[c0 + u * 4 + 3][r] = v.w;
    }
  }
  {
    int r = tid >> 3, c0 = (tid & 7) * 16;
#pragma unroll
    for (int u = 0; u < 4; u++) {
      float4 v = *(const float4*)(comb + (size_t)(j0 + r) * 256 + 128 + c0 + u * 4);
      hjs[c0 + u * 4 + 0][r] = v.x; hjs[c0 + u * 4 + 1][r] = v.y;
      hjs[c0 + u * 4 + 2][r] = v.z; hjs[c0 + u * 4 + 3][r] = v.w;
    }
  }
  __syncthreads();
  const int il = (tid & 15) * 4, jl = (tid >> 4) * 2;
  float acc[4][2] = {{0.f,0.f},{0.f,0.f},{0.f,0.f},{0.f,0.f}};
  for (int e = 0; e < 128; e++) {
    float4 a = *(const float4*)&his[e][il];
    float2 bv = *(const float2*)&hjs[e][jl];
    float we = w[e];
    float av[4] = {a.x, a.y, a.z, a.w};
    float bb[2] = {bv.x, bv.y};
#pragma unroll
    for (int ii = 0; ii < 4; ii++)
#pragma unroll
      for (int jj = 0; jj < 2; jj++)
        acc[ii][jj] += fmaxf(av[ii] + bb[jj], 0.f) * we;
  }
  float eb = e2b[0];
#pragma unroll
  for (int ii = 0; ii < 4; ii++) {
    float2 vv = make_float2(acc[ii][0] + eb, acc[ii][1] + eb);
    *(float2*)(out + (size_t)(i0 + il + ii) * 1024 + j0 + jl) = vv;
  }
}

// ---------------------------------------------------------------------------
extern "C" void kernel_launch(void* const* d_in, const int* in_sizes, int n_in,
                              void* d_out, int out_size, void* d_ws, size_t ws_size,
                              hipStream_t stream)
{
  const float* x        = (const float*)d_in[0];
  const float* conv1_w  = (const float*)d_in[1];
  const float* conv1_b  = (const float*)d_in[2];
  const float* bn1_g    = (const float*)d_in[3];
  const float* bn1_b    = (const float*)d_in[4];
  const float* bn1_m    = (const float*)d_in[5];
  const float* bn1_v    = (const float*)d_in[6];
  const float* conv2_w  = (const float*)d_in[7];
  const float* conv2_b  = (const float*)d_in[8];
  const float* bn2_g    = (const float*)d_in[9];
  const float* bn2_b    = (const float*)d_in[10];
  const float* bn2_m    = (const float*)d_in[11];
  const float* bn2_v    = (const float*)d_in[12];
  const float* proj_w   = (const float*)d_in[13];
  const float* proj_b   = (const float*)d_in[14];
  const float* attn_in_w  = (const float*)d_in[15];
  const float* attn_in_b  = (const float*)d_in[16];
  const float* attn_out_w = (const float*)d_in[17];
  const float* attn_out_b = (const float*)d_in[18];
  const float* ln1_g    = (const float*)d_in[19];
  const float* ln1_b    = (const float*)d_in[20];
  const float* ff1_w    = (const float*)d_in[21];
  const float* ff1_b    = (const float*)d_in[22];
  const float* ff2_w    = (const float*)d_in[23];
  const float* ff2_b    = (const float*)d_in[24];
  const float* ln2_g    = (const float*)d_in[25];
  const float* ln2_b    = (const float*)d_in[26];
  const float* nh1_w    = (const float*)d_in[27];
  const float* nh1_b    = (const float*)d_in[28];
  const float* nh2_w    = (const float*)d_in[29];
  const float* nh2_b    = (const float*)d_in[30];
  const float* e1_w     = (const float*)d_in[31];
  const float* e1_b     = (const float*)d_in[32];
  const float* e2_w     = (const float*)d_in[33];
  const float* e2_b     = (const float*)d_in[34];
  const float* p1_w     = (const float*)d_in[35];
  const float* p1_b     = (const float*)d_in[36];
  const float* p2_w     = (const float*)d_in[37];
  const float* p2_b     = (const float*)d_in[38];

  float* ws = (float*)d_ws;

  // Fixed arena (f32 units), total 2,466,048 f32 = 9.41 MiB (<= 9.5 proven).
  u16*  wbf    = (u16*)ws;                       // 1392640 u16
  float* wbias = ws + 696320;                    // 256 f32
  float* z     = ws + 696576;                    // 131072
  u16*  z_bf   = (u16*)(ws + 827648);            // 131072 u16
  float* tS    = ws + 893184;                    // 131072
  u16*  t_bf   = (u16*)(ws + 1024256);           // 131072 u16
  u16*  qkv_bf = (u16*)(ws + 1089792);           // 393216 u16
  float* pre   = ws + 1286400;                   // 131072 f32
  float* R     = ws + 1417472;                   // 1048576 f32 shared region
  u16*  pooled_bf = (u16*)R;
  u16*  attnO  = (u16*)R;
  u16*  vt     = (u16*)R + 131072;
  u16*  fb     = (u16*)R;
  float* nhmid = R;
  float* e1out = R + 131072;
  u16*  pmid   = (u16*)(R + 393216);

  float* out_node = (float*)d_out;
  float* out_edge = out_node + 3072;
  float* out_proj = out_edge + 1048576;

  float* nullf = nullptr; u16* nullb = nullptr;

  wconv_kernel<<<1361, 256, 0, stream>>>(
      proj_w, attn_in_w, attn_out_w, ff1_w, ff2_w, nh1_w, e1_w, e1_b,
      p1_w, p2_w, wbf, wbias);

  encoder_kernel<<<2048, 256, 0, stream>>>(
      x, conv1_w, conv1_b, bn1_g, bn1_b, bn1_m, bn1_v,
      conv2_w, conv2_b, bn2_g, bn2_b, bn2_m, bn2_v, pooled_bf);

  // z = pooled @ proj_w^T + proj_b
  mm_kernel<2, 1024, false, false><<<dim3(32, 4), 64, 0, stream>>>(
      pooled_bf, 1024, wbf, 1024, proj_b, z, z_bf, nullb, 128);

  for (int l = 0; l < 2; l++) {
    const float* resIn = l ? tS : z;
    const u16* tin_bf = l ? t_bf : z_bf;
    mm_kernel<4, 128, false, true><<<dim3(32, 6), 64, 0, stream>>>(
        tin_bf, 128, wbf + 131072 + l * 49152, 128, attn_in_b + l * 384,
        nullf, qkv_bf, vt, 384);
    attn_kernel<<<dim3(64, 4), 64, 0, stream>>>(qkv_bf, vt, attnO);
    owl_kernel<<<32, 256, 0, stream>>>(
        attnO, wbf + 229376 + l * 16384, attn_out_b + l * 128, resIn,
        tS, t_bf, ln1_g + l * 128, ln1_b + l * 128);
    mm_kernel<4, 128, true, false><<<dim3(32, 32), 64, 0, stream>>>(
        t_bf, 128, wbf + 262144 + l * 262144, 128, ff1_b + l * 2048,
        nullf, fb, nullb, 2048);
    mm_kernel<4, 2048, false, false><<<dim3(32, 2), 64, 0, stream>>>(
        fb, 2048, wbf + 786432 + l * 262144, 2048, ff2_b + l * 128,
        pre, nullb, nullb, 128);
    ln2r_kernel<<<256, 256, 0, stream>>>(
        pre, tS, t_bf, ln2_g + l * 128, ln2_b + l * 128);
  }

  // node head
  mm_kernel<2, 128, true, false><<<dim3(32, 4), 64, 0, stream>>>(
      t_bf, 128, wbf + 1310720, 128, nh1_b, nhmid, nullb, nullb, 128);
  nh2_kernel<<<16, 256, 0, stream>>>(nhmid, nh2_w, nh2_b, out_node);

  // edge MLP
  mm_kernel<2, 128, false, false><<<dim3(32, 8), 64, 0, stream>>>(
      t_bf, 128, wbf + 1327104, 128, wbias, e1out, nullb, nullb, 256);
  edge_kernel<<<dim3(16, 32), 256, 0, stream>>>(e1out, e2_w, e2_b, out_edge);

  // projector (on z)
  mm_kernel<2, 128, true, false><<<dim3(32, 4), 64, 0, stream>>>(
      z_bf, 128, wbf + 1359872, 128, p1_b, nullf, pmid, nullb, 128);
  mm_kernel<2, 128, false, false><<<dim3(32, 4), 64, 0, stream>>>(
      pmid, 128, wbf + 1376256, 128, p2_b, out_proj, nullb, nullb, 128);
}